// Round 6
// baseline (871.403 us; speedup 1.0000x reference)
//
#include <hip/hip_runtime.h>

// GCN 2-layer, edge-streamed LDS aggregation with src-swept gathers.
// Pipeline: colsum -> bucketA (dst-bucket edges) -> sortB (src-sort within
// bucket + deg/dis) -> cvec -> gemm1 (h1s bf16, dis-prescaled) ->
// aggB (layer1 LDS accumulate + relu + @W2 fused) -> agg2 (layer2 -> out).
// Identity: [x|mean]@W1 = x@W1[:64] + c, c = mean@W1[64:].
// Pre-scaling: h1s[s]=dis[s]*(xW1+c)[s]; h2s[s]=dis[s]*(relu(.)@W2)[s].

#define NPB        256     // nodes per bucket
#define NPB_SHIFT  8
#define BKT_CAP    5376    // mean 4096 + 20 sigma
#define CHUNK      4096    // edges per bucketA block
#define EPT        8       // CHUNK / 512 threads
#define MAXB       512     // >= nbkt (391), power of 2 for scans

__device__ __forceinline__ unsigned short f2bf(float v) {
    unsigned u = __float_as_uint(v);
    u += 0x7FFFu + ((u >> 16) & 1u);   // round-to-nearest-even
    return (unsigned short)(u >> 16);
}
__device__ __forceinline__ float bf2f(unsigned short h) {
    return __uint_as_float((unsigned)h << 16);
}

// ---------- column sums of x (for mean) ----------
__global__ void colsum_kernel(const float* __restrict__ x, float* __restrict__ sums,
                              long long total) {
    int tid = threadIdx.x;
    long long g = (long long)blockIdx.x * blockDim.x + tid;
    long long stride = (long long)gridDim.x * blockDim.x;  // multiple of 64 -> column fixed
    float acc = 0.f;
    for (; g < total; g += stride) acc += x[g];
    __shared__ float s[256];
    s[tid] = acc;
    __syncthreads();
    if (tid < 64) {
        float v = s[tid] + s[tid + 64] + s[tid + 128] + s[tid + 192];
        atomicAdd(&sums[tid], v);
    }
}

// ---------- pass A: LDS multi-split of edges into 256-node dst buckets ----------
__global__ __launch_bounds__(512) void bucketA_kernel(
        const int* __restrict__ src, const int* __restrict__ dst,
        int e, int nbkt, int2* __restrict__ pairs, int* __restrict__ cursor) {
    __shared__ int cnt[MAXB], sb[MAXB], gpos[MAXB];
    __shared__ int2 stage[CHUNK];
    __shared__ unsigned short bb[CHUNK];
    int tid = threadIdx.x;
    int chunkStart = blockIdx.x * CHUNK;
    int v = e - chunkStart;
    if (v > CHUNK) v = CHUNK;
    for (int i = tid; i < MAXB; i += 512) cnt[i] = 0;
    __syncthreads();
    int myb[EPT], myoff[EPT], mys[EPT], myd[EPT];
#pragma unroll
    for (int t = 0; t < EPT; ++t) {
        int i = chunkStart + t * 512 + tid;
        myb[t] = -1;
        if (i < e) {
            mys[t] = src[i];
            myd[t] = dst[i];
            myb[t] = myd[t] >> NPB_SHIFT;
            myoff[t] = atomicAdd(&cnt[myb[t]], 1);
        }
    }
    __syncthreads();
    sb[tid] = cnt[tid];
    __syncthreads();
    for (int off = 1; off < MAXB; off <<= 1) {
        int t = (tid >= off) ? sb[tid - off] : 0;
        __syncthreads();
        sb[tid] += t;
        __syncthreads();
    }
    if (tid < nbkt) {
        int excl = tid ? sb[tid - 1] : 0;
        int gb = atomicAdd(&cursor[tid], cnt[tid]);
        gpos[tid] = tid * BKT_CAP + gb - excl;
        cnt[tid] = excl;  // reuse as stage base
    }
    __syncthreads();
#pragma unroll
    for (int t = 0; t < EPT; ++t) {
        if (myb[t] >= 0) {
            int p = cnt[myb[t]] + myoff[t];
            stage[p] = make_int2(mys[t], myd[t]);
            bb[p] = (unsigned short)myb[t];
        }
    }
    __syncthreads();
    for (int j = tid; j < v; j += 512) {
        int bk = bb[j];
        int wi = gpos[bk] + j;
        if (wi < (bk + 1) * BKT_CAP) pairs[wi] = stage[j];  // contiguous runs
    }
}

// ---------- pass B: per-bucket src-sort (in place) + deg -> dis ----------
__global__ __launch_bounds__(512) void sortB_kernel(
        int2* __restrict__ pairs, const int* __restrict__ cursor,
        float* __restrict__ dis, int n) {
    __shared__ int2 stage[BKT_CAP];   // 43 KB
    __shared__ int ldeg[NPB];
    __shared__ int scur[MAXB];
    int b = blockIdx.x, tid = threadIdx.x;
    int node0 = b << NPB_SHIFT;
    int cnt_b = cursor[b];
    if (cnt_b > BKT_CAP) cnt_b = BKT_CAP;
    int2* mp = pairs + (size_t)b * BKT_CAP;
    for (int i = tid; i < NPB; i += 512) ldeg[i] = 0;
    scur[tid] = 0;
    __syncthreads();
    for (int i = tid; i < cnt_b; i += 512) {
        int2 p = mp[i];
        atomicAdd(&ldeg[p.y - node0], 1);
        atomicAdd(&scur[p.x >> NPB_SHIFT], 1);   // src-class histogram
    }
    __syncthreads();
    for (int i = tid; i < NPB; i += 512) {
        int node = node0 + i;
        if (node < n) {
            int d = ldeg[i];
            dis[node] = d > 0 ? rsqrtf((float)d) : 0.f;
        }
    }
    int myc = scur[tid];
    __syncthreads();
    // inclusive scan of class counts
    for (int off = 1; off < MAXB; off <<= 1) {
        int t = (tid >= off) ? scur[tid - off] : 0;
        __syncthreads();
        scur[tid] += t;
        __syncthreads();
    }
    int base = scur[tid] - myc;   // exclusive
    __syncthreads();
    scur[tid] = base;
    __syncthreads();
    for (int i = tid; i < cnt_b; i += 512) {
        int2 p = mp[i];
        int pos = atomicAdd(&scur[p.x >> NPB_SHIFT], 1);
        stage[pos] = p;
    }
    __syncthreads();
    for (int i = tid; i < cnt_b; i += 512) mp[i] = stage[i];  // coalesced writeback
}

// ---------- c = mean @ W1[64:] ----------
__global__ void cvec_kernel(const float* __restrict__ sums, const float* __restrict__ W1,
                            float* __restrict__ c, int n) {
    int j = threadIdx.x;  // 64 threads
    float inv_n = 1.0f / (float)n;
    float acc = 0.f;
    for (int k = 0; k < 64; ++k) acc += (sums[k] * inv_n) * W1[(64 + k) * 64 + j];
    c[j] = acc;
}

// ---------- h1s(bf16) = dis[row] * (x @ W1[:64] + c); 4 rows x 4 cols/thread ----------
__global__ __launch_bounds__(256, 4) void gemm1_kernel(
        const float* __restrict__ x, const float* __restrict__ W1,
        const float* __restrict__ c, const float* __restrict__ dis,
        unsigned short* __restrict__ h1s, int n) {
    __shared__ float Ws[64 * 64];
    __shared__ float Xs[64 * 68];
    int tid = threadIdx.x;
    int row0 = blockIdx.x * 64;
    {
        const float4* w4 = (const float4*)W1;
        float4* s4 = (float4*)Ws;
        for (int i = tid; i < 1024; i += 256) s4[i] = w4[i];
    }
    for (int i = tid; i < 1024; i += 256) {
        int r = i >> 4, c4 = (i & 15) * 4;
        int gr = row0 + r;
        float4 xv = make_float4(0.f, 0.f, 0.f, 0.f);
        if (gr < n) xv = *(const float4*)&x[(size_t)gr * 64 + c4];
        *(float4*)&Xs[r * 68 + c4] = xv;
    }
    __syncthreads();
    int c16 = tid & 15;
    int rb = (tid >> 4) * 4;
    float4 cj = ((const float4*)c)[c16];
    float4 a0 = cj, a1 = cj, a2 = cj, a3 = cj;
#pragma unroll 4
    for (int k = 0; k < 64; ++k) {
        float4 w = *(const float4*)&Ws[k * 64 + c16 * 4];
        float x0 = Xs[(rb + 0) * 68 + k];
        float x1 = Xs[(rb + 1) * 68 + k];
        float x2 = Xs[(rb + 2) * 68 + k];
        float x3 = Xs[(rb + 3) * 68 + k];
        a0.x += x0 * w.x; a0.y += x0 * w.y; a0.z += x0 * w.z; a0.w += x0 * w.w;
        a1.x += x1 * w.x; a1.y += x1 * w.y; a1.z += x1 * w.z; a1.w += x1 * w.w;
        a2.x += x2 * w.x; a2.y += x2 * w.y; a2.z += x2 * w.z; a2.w += x2 * w.w;
        a3.x += x3 * w.x; a3.y += x3 * w.y; a3.z += x3 * w.z; a3.w += x3 * w.w;
    }
    float4 accs[4] = {a0, a1, a2, a3};
#pragma unroll
    for (int r = 0; r < 4; ++r) {
        int gr = row0 + rb + r;
        if (gr < n) {
            float dv = dis[gr];
            float4 o = accs[r];
            ushort4 hs;
            hs.x = f2bf(o.x * dv);
            hs.y = f2bf(o.y * dv);
            hs.z = f2bf(o.z * dv);
            hs.w = f2bf(o.w * dv);
            *(ushort4*)&h1s[(size_t)gr * 64 + c16 * 4] = hs;
        }
    }
}

// ---------- layer-1 edge-streamed LDS aggregate + bias/relu/@W2 epilogue ----------
__global__ __launch_bounds__(256) void aggB_kernel(
        const int2* __restrict__ pairs, const int* __restrict__ cursor,
        const float* __restrict__ dis, const unsigned short* __restrict__ h1s,
        const float* __restrict__ b1, const float* __restrict__ W2,
        float2* __restrict__ h2s, int n) {
    __shared__ float agg[NPB * 64];   // 65,536 B exactly
    int b = blockIdx.x, tid = threadIdx.x;
    int node0 = b << NPB_SHIFT;
    int cnt_b = cursor[b];
    if (cnt_b > BKT_CAP) cnt_b = BKT_CAP;
    for (int i = tid; i < NPB * 64; i += 256) agg[i] = 0.f;
    __syncthreads();
    const int2* mp = pairs + (size_t)b * BKT_CAP;
    int g = tid >> 4;                                        // 16 edge groups
    int chunk = ((tid & 15) + ((g & 1) << 2)) & 15;          // stagger: 4-way not 8-way
    int fb = chunk * 4;
    int i = g;
    int2 p;
    if (i < cnt_b) p = mp[i];
    while (i < cnt_b) {                      // src-sorted: coherent h1s sweep
        int inext = i + 16;
        int2 pn = p;
        if (inext < cnt_b) pn = mp[inext];   // prefetch next pair
        ushort4 h = *(const ushort4*)&h1s[((size_t)p.x << 6) + fb];
        float* row = &agg[((p.y - node0) << 6) + fb];
        atomicAdd(&row[0], bf2f(h.x));
        atomicAdd(&row[1], bf2f(h.y));
        atomicAdd(&row[2], bf2f(h.z));
        atomicAdd(&row[3], bf2f(h.w));
        i = inext;
        p = pn;
    }
    __syncthreads();
    int node = node0 + tid;
    if (node < n) {
        float di = dis[node];
        const float* row = &agg[tid << 6];
        float v0 = 0.f, v1 = 0.f;
#pragma unroll 8
        for (int ff = 0; ff < 64; ++ff) {
            int f = (ff + tid) & 63;         // staggered: conflict-free LDS reads
            float t = fmaxf(di * row[f] + b1[f], 0.f);
            v0 += t * W2[f * 2 + 0];
            v1 += t * W2[f * 2 + 1];
        }
        h2s[node] = make_float2(di * v0, di * v1);
    }
}

// ---------- layer-2 edge-streamed LDS aggregate -> out ----------
__global__ __launch_bounds__(256) void agg2_kernel(
        const int2* __restrict__ pairs, const int* __restrict__ cursor,
        const float* __restrict__ dis, const float2* __restrict__ h2s,
        const float* __restrict__ b2, float2* __restrict__ out, int n) {
    __shared__ float agg[NPB * 2];
    int b = blockIdx.x, tid = threadIdx.x;
    int node0 = b << NPB_SHIFT;
    int cnt_b = cursor[b];
    if (cnt_b > BKT_CAP) cnt_b = BKT_CAP;
    for (int i = tid; i < NPB * 2; i += 256) agg[i] = 0.f;
    __syncthreads();
    const int2* mp = pairs + (size_t)b * BKT_CAP;
    for (int i = tid; i < cnt_b; i += 256) {
        int2 p = mp[i];
        float2 h = h2s[p.x];                 // src-sorted -> swept 8 B loads
        int dl = (p.y - node0) * 2;
        atomicAdd(&agg[dl + 0], h.x);
        atomicAdd(&agg[dl + 1], h.y);
    }
    __syncthreads();
    int node = node0 + tid;
    if (node < n) {
        float di = dis[node];
        out[node] = make_float2(di * agg[tid * 2 + 0] + b2[0],
                                di * agg[tid * 2 + 1] + b2[1]);
    }
}

extern "C" void kernel_launch(void* const* d_in, const int* in_sizes, int n_in,
                              void* d_out, int out_size, void* d_ws, size_t ws_size,
                              hipStream_t stream) {
    const float* x  = (const float*)d_in[0];
    const int*   ei = (const int*)d_in[1];
    const float* W1 = (const float*)d_in[2];
    const float* b1 = (const float*)d_in[3];
    const float* W2 = (const float*)d_in[4];
    const float* b2 = (const float*)d_in[5];
    float2* out = (float2*)d_out;

    const int n = in_sizes[0] / 64;   // 100000
    const int e = in_sizes[1] / 2;    // 1600000
    const int* srcI = ei;
    const int* dstI = ei + e;
    const int nbkt = (n + NPB - 1) >> NPB_SHIFT;   // 391

    // workspace layout (256-B aligned segments), ~30.9 MB total
    char* p = (char*)d_ws;
    float* dis    = (float*)p;  p += ((size_t)n * 4 + 255) & ~255ull;
    float* sums   = (float*)p;  p += 256;
    float* cvec   = (float*)p;  p += 256;
    int* cursor   = (int*)p;    p += 2048;
    int2* pairs   = (int2*)p;   p += ((size_t)nbkt * BKT_CAP * 8 + 255) & ~255ull;
    unsigned short* h1s = (unsigned short*)p;  p += ((size_t)n * 64 * 2 + 255) & ~255ull;
    float2* h2s   = (float2*)p;

    hipMemsetAsync(cursor, 0, 2048, stream);
    hipMemsetAsync(sums, 0, 256, stream);

    const int nchunks = (e + CHUNK - 1) / CHUNK;   // 391

    colsum_kernel<<<1024, 256, 0, stream>>>(x, sums, (long long)n * 64);
    bucketA_kernel<<<nchunks, 512, 0, stream>>>(srcI, dstI, e, nbkt, pairs, cursor);
    sortB_kernel<<<nbkt, 512, 0, stream>>>(pairs, cursor, dis, n);
    cvec_kernel<<<1, 64, 0, stream>>>(sums, W1, cvec, n);
    gemm1_kernel<<<(n + 63) / 64, 256, 0, stream>>>(x, W1, cvec, dis, h1s, n);
    aggB_kernel<<<nbkt, 256, 0, stream>>>(pairs, cursor, dis, h1s, b1, W2, h2s, n);
    agg2_kernel<<<nbkt, 256, 0, stream>>>(pairs, cursor, dis, h2s, b2, out, n);
}

// Round 7
// 662.708 us; speedup vs baseline: 1.3149x; 1.3149x over previous
//
#include <hip/hip_runtime.h>

// GCN 2-layer, CSR-by-dst gather formulation; h1s in bf16. (R4 skeleton.)
// R6: gemm1 uses b128 LDS reads for both X and W; pairs packed to 4 B.
// out = A_hat( relu( A_hat( [x|mean]@W1 ) + b1 ) @ W2 ) + b2
// Identity: [x|mean]@W1 = x@W1[:64] + c, c = mean@W1[64:].
// Pre-scaling: h1s[s] = dis[s]*(xW1+c)[s];  h2s[s] = dis[s]*(relu(.)@W2)[s].

#define BKT        128     // dst-range buckets
#define BKT_SHIFT  10      // 1024 nodes per bucket
#define NPB        1024
#define BKT_CAP    18432   // mean 12500 + >50 sigma
#define CHUNK      2048    // edges per bucketA block
#define EPT        8       // edges per thread in bucketA

__device__ __forceinline__ unsigned short f2bf(float v) {
    unsigned u = __float_as_uint(v);
    u += 0x7FFFu + ((u >> 16) & 1u);   // round-to-nearest-even
    return (unsigned short)(u >> 16);
}
__device__ __forceinline__ float bf2f(unsigned short h) {
    return __uint_as_float((unsigned)h << 16);
}

// ---------- column sums of x (for mean) ----------
__global__ void colsum_kernel(const float* __restrict__ x, float* __restrict__ sums,
                              long long total) {
    int tid = threadIdx.x;
    long long g = (long long)blockIdx.x * blockDim.x + tid;
    long long stride = (long long)gridDim.x * blockDim.x;  // multiple of 64 -> column fixed
    float acc = 0.f;
    for (; g < total; g += stride) acc += x[g];
    __shared__ float s[256];
    s[tid] = acc;
    __syncthreads();
    if (tid < 64) {
        float v = s[tid] + s[tid + 64] + s[tid + 128] + s[tid + 192];
        atomicAdd(&sums[tid], v);
    }
}

// ---------- pass A: LDS multi-split; packed 4-B records (src<<10 | dst&1023) ----------
__global__ void bucketA_kernel(const int* __restrict__ src, const int* __restrict__ dst,
                               int e, unsigned* __restrict__ pairs, int* __restrict__ cursor) {
    __shared__ int cnt[BKT], sb[BKT], gpos[BKT];
    __shared__ unsigned stage[CHUNK];
    __shared__ unsigned char bb[CHUNK];
    int tid = threadIdx.x;
    int chunkStart = blockIdx.x * CHUNK;
    int v = e - chunkStart;
    if (v > CHUNK) v = CHUNK;
    if (tid < BKT) cnt[tid] = 0;
    __syncthreads();
    int myb[EPT], myoff[EPT];
    unsigned myp[EPT];
#pragma unroll
    for (int t = 0; t < EPT; ++t) {
        int i = chunkStart + t * 256 + tid;
        myb[t] = -1;
        if (i < e) {
            int s = src[i], d = dst[i];
            myb[t] = d >> BKT_SHIFT;
            myp[t] = ((unsigned)s << BKT_SHIFT) | (unsigned)(d & (NPB - 1));
            myoff[t] = atomicAdd(&cnt[myb[t]], 1);
        }
    }
    __syncthreads();
    if (tid < BKT) sb[tid] = cnt[tid];
    __syncthreads();
    for (int off = 1; off < BKT; off <<= 1) {
        int t = (tid < BKT && tid >= off) ? sb[tid - off] : 0;
        __syncthreads();
        if (tid < BKT) sb[tid] += t;
        __syncthreads();
    }
    if (tid < BKT) {
        int excl = tid ? sb[tid - 1] : 0;
        int gb = atomicAdd(&cursor[tid], cnt[tid]);
        gpos[tid] = tid * BKT_CAP + gb - excl;
        cnt[tid] = excl;  // reuse as stage base
    }
    __syncthreads();
#pragma unroll
    for (int t = 0; t < EPT; ++t) {
        if (myb[t] >= 0) {
            int p = cnt[myb[t]] + myoff[t];
            stage[p] = myp[t];
            bb[p] = (unsigned char)myb[t];
        }
    }
    __syncthreads();
    for (int j = tid; j < v; j += 256) {
        pairs[gpos[bb[j]] + j] = stage[j];  // contiguous runs per bucket
    }
}

// ---------- pass B: per-bucket hist + scan + ordered eidx fill; emits dis + rowstart ----------
__global__ void csrB_kernel(const unsigned* __restrict__ pairs, const int* __restrict__ cursor,
                            float* __restrict__ dis, int* __restrict__ rowstart,
                            int* __restrict__ eidx, int n) {
    __shared__ int ldeg[NPB];
    __shared__ int lcur[NPB];
    __shared__ int scanbuf[512];
    __shared__ int s_ebase;
    int b = blockIdx.x;
    int tid = threadIdx.x;
    int node0 = b << BKT_SHIFT;
    if (node0 >= n) return;
    int nl = n - node0;
    if (nl > NPB) nl = NPB;
    int cnt_b = cursor[b];
    for (int i = tid; i < NPB; i += 512) ldeg[i] = 0;
    if (tid == 0) {
        int s = 0;
        for (int q = 0; q < b; ++q) s += cursor[q];
        s_ebase = s;
    }
    __syncthreads();
    const unsigned* mp = pairs + (size_t)b * BKT_CAP;
    for (int i = tid; i < cnt_b; i += 512)
        atomicAdd(&ldeg[mp[i] & (NPB - 1)], 1);
    __syncthreads();
    int base = tid * 2;
    int ts = ldeg[base] + ldeg[base + 1];
    scanbuf[tid] = ts;
    __syncthreads();
    for (int off = 1; off < 512; off <<= 1) {
        int t = (tid >= off) ? scanbuf[tid - off] : 0;
        __syncthreads();
        scanbuf[tid] += t;
        __syncthreads();
    }
    int ex = tid ? scanbuf[tid - 1] : 0;
    int ebase = s_ebase;
#pragma unroll
    for (int j = 0; j < 2; ++j) {
        lcur[base + j] = ex;
        if (base + j < nl) {
            int dv = ldeg[base + j];
            rowstart[node0 + base + j] = ebase + ex;
            dis[node0 + base + j] = dv > 0 ? rsqrtf((float)dv) : 0.f;
        }
        ex += ldeg[base + j];
    }
    if (tid == 0 && node0 + NPB >= n)          // last bucket: close the CSR
        rowstart[n] = ebase + cnt_b;
    __syncthreads();
    for (int i = tid; i < cnt_b; i += 512) {
        unsigned p = mp[i];
        int pos = atomicAdd(&lcur[p & (NPB - 1)], 1);
        eidx[ebase + pos] = (int)(p >> BKT_SHIFT);  // contiguous ~65 KB window
    }
}

// ---------- c = mean @ W1[64:] ----------
__global__ void cvec_kernel(const float* __restrict__ sums, const float* __restrict__ W1,
                            float* __restrict__ c, int n) {
    int j = threadIdx.x;  // 64 threads
    float inv_n = 1.0f / (float)n;
    float acc = 0.f;
    for (int k = 0; k < 64; ++k) acc += (sums[k] * inv_n) * W1[(64 + k) * 64 + j];
    c[j] = acc;
}

// ---------- h1s(bf16) = dis[row] * (x @ W1[:64] + c); all-b128 LDS inner loop ----------
__global__ __launch_bounds__(256, 4) void gemm1_kernel(
        const float* __restrict__ x, const float* __restrict__ W1,
        const float* __restrict__ c, const float* __restrict__ dis,
        unsigned short* __restrict__ h1s, int n) {
    __shared__ float Ws[64 * 64];   // [k][j]
    __shared__ float Xs[64 * 68];   // stride 68 (mult of 4: float4-aligned)
    int tid = threadIdx.x;
    int row0 = blockIdx.x * 64;
    {
        const float4* w4 = (const float4*)W1;
        float4* s4 = (float4*)Ws;
        for (int i = tid; i < 1024; i += 256) s4[i] = w4[i];
    }
    for (int i = tid; i < 1024; i += 256) {
        int r = i >> 4, c4 = (i & 15) * 4;
        int gr = row0 + r;
        float4 xv = make_float4(0.f, 0.f, 0.f, 0.f);
        if (gr < n) xv = *(const float4*)&x[(size_t)gr * 64 + c4];
        *(float4*)&Xs[r * 68 + c4] = xv;
    }
    __syncthreads();
    int c16 = tid & 15;
    int rb = (tid >> 4) * 4;
    float4 cj = ((const float4*)c)[c16];
    float4 a0 = cj, a1 = cj, a2 = cj, a3 = cj;
    for (int k4 = 0; k4 < 64; k4 += 4) {
        float4 x0 = *(const float4*)&Xs[(rb + 0) * 68 + k4];   // b128, broadcast in-group
        float4 x1 = *(const float4*)&Xs[(rb + 1) * 68 + k4];
        float4 x2 = *(const float4*)&Xs[(rb + 2) * 68 + k4];
        float4 x3 = *(const float4*)&Xs[(rb + 3) * 68 + k4];
        float4 w0 = *(const float4*)&Ws[(k4 + 0) * 64 + c16 * 4];  // b128, 2-way = free
        float4 w1 = *(const float4*)&Ws[(k4 + 1) * 64 + c16 * 4];
        float4 w2 = *(const float4*)&Ws[(k4 + 2) * 64 + c16 * 4];
        float4 w3 = *(const float4*)&Ws[(k4 + 3) * 64 + c16 * 4];
        a0.x += x0.x*w0.x + x0.y*w1.x + x0.z*w2.x + x0.w*w3.x;
        a0.y += x0.x*w0.y + x0.y*w1.y + x0.z*w2.y + x0.w*w3.y;
        a0.z += x0.x*w0.z + x0.y*w1.z + x0.z*w2.z + x0.w*w3.z;
        a0.w += x0.x*w0.w + x0.y*w1.w + x0.z*w2.w + x0.w*w3.w;
        a1.x += x1.x*w0.x + x1.y*w1.x + x1.z*w2.x + x1.w*w3.x;
        a1.y += x1.x*w0.y + x1.y*w1.y + x1.z*w2.y + x1.w*w3.y;
        a1.z += x1.x*w0.z + x1.y*w1.z + x1.z*w2.z + x1.w*w3.z;
        a1.w += x1.x*w0.w + x1.y*w1.w + x1.z*w2.w + x1.w*w3.w;
        a2.x += x2.x*w0.x + x2.y*w1.x + x2.z*w2.x + x2.w*w3.x;
        a2.y += x2.x*w0.y + x2.y*w1.y + x2.z*w2.y + x2.w*w3.y;
        a2.z += x2.x*w0.z + x2.y*w1.z + x2.z*w2.z + x2.w*w3.z;
        a2.w += x2.x*w0.w + x2.y*w1.w + x2.z*w2.w + x2.w*w3.w;
        a3.x += x3.x*w0.x + x3.y*w1.x + x3.z*w2.x + x3.w*w3.x;
        a3.y += x3.x*w0.y + x3.y*w1.y + x3.z*w2.y + x3.w*w3.y;
        a3.z += x3.x*w0.z + x3.y*w1.z + x3.z*w2.z + x3.w*w3.z;
        a3.w += x3.x*w0.w + x3.y*w1.w + x3.z*w2.w + x3.w*w3.w;
    }
    float4 accs[4] = {a0, a1, a2, a3};
#pragma unroll
    for (int r = 0; r < 4; ++r) {
        int gr = row0 + rb + r;
        if (gr < n) {
            float dv = dis[gr];
            float4 o = accs[r];
            ushort4 hs;
            hs.x = f2bf(o.x * dv);
            hs.y = f2bf(o.y * dv);
            hs.z = f2bf(o.z * dv);
            hs.w = f2bf(o.w * dv);
            *(ushort4*)&h1s[(size_t)gr * 64 + c16 * 4] = hs;
        }
    }
}

// ---------- layer-1 gather: 16 lanes per edge, ushort4 per lane; one wave/node ----------
__global__ void gather1_kernel(const int* __restrict__ rowstart,
                               const int* __restrict__ eidx, const float* __restrict__ dis,
                               const unsigned short* __restrict__ h1s,
                               const float* __restrict__ b1, const float* __restrict__ W2,
                               float* __restrict__ h2s, int n) {
    int lane = threadIdx.x & 63;
    int node = blockIdx.x * 4 + (threadIdx.x >> 6);
    if (node >= n) return;
    int rs = rowstart[node];
    int re = rowstart[node + 1];
    int dn = re - rs;
    int m = dn < 64 ? dn : 64;
    int eHeld = (lane < m) ? eidx[rs + lane] : 0;  // one coalesced load for <=64 edges
    int g  = lane >> 4;        // edge subgroup 0..3
    int fb = (lane & 15) * 4;  // feature base
    float4 acc = make_float4(0.f, 0.f, 0.f, 0.f);
    int j = 0;
    for (; j + 8 <= m; j += 8) {           // 8 edges per iter, 2 loads in flight
        int sa = __shfl(eHeld, j + g, 64);
        int sb = __shfl(eHeld, j + 4 + g, 64);
        ushort4 ha = *(const ushort4*)&h1s[((size_t)sa << 6) + fb];
        ushort4 hb = *(const ushort4*)&h1s[((size_t)sb << 6) + fb];
        acc.x += bf2f(ha.x) + bf2f(hb.x);
        acc.y += bf2f(ha.y) + bf2f(hb.y);
        acc.z += bf2f(ha.z) + bf2f(hb.z);
        acc.w += bf2f(ha.w) + bf2f(hb.w);
    }
    for (; j < m; j += 4) {                // ragged tail, 0..2 iters
        int jj = j + g;
        int s = __shfl(eHeld, jj < m ? jj : 0, 64);
        if (jj < m) {
            ushort4 h = *(const ushort4*)&h1s[((size_t)s << 6) + fb];
            acc.x += bf2f(h.x);
            acc.y += bf2f(h.y);
            acc.z += bf2f(h.z);
            acc.w += bf2f(h.w);
        }
    }
    for (int t = 64; t < dn; ++t) {        // deg > 64: astronomically rare here
        if (g == 0) {
            int s = eidx[rs + t];
            ushort4 h = *(const ushort4*)&h1s[((size_t)s << 6) + fb];
            acc.x += bf2f(h.x);
            acc.y += bf2f(h.y);
            acc.z += bf2f(h.z);
            acc.w += bf2f(h.w);
        }
    }
    // reduce across the 4 edge subgroups
    acc.x += __shfl_xor(acc.x, 16, 64); acc.x += __shfl_xor(acc.x, 32, 64);
    acc.y += __shfl_xor(acc.y, 16, 64); acc.y += __shfl_xor(acc.y, 32, 64);
    acc.z += __shfl_xor(acc.z, 16, 64); acc.z += __shfl_xor(acc.z, 32, 64);
    acc.w += __shfl_xor(acc.w, 16, 64); acc.w += __shfl_xor(acc.w, 32, 64);
    float di = dis[node];
    float4 bv = ((const float4*)b1)[lane & 15];
    float4 w0 = ((const float4*)W2)[(lane & 15) * 2];
    float4 w1 = ((const float4*)W2)[(lane & 15) * 2 + 1];
    float t0 = fmaxf(di * acc.x + bv.x, 0.f);
    float t1 = fmaxf(di * acc.y + bv.y, 0.f);
    float t2 = fmaxf(di * acc.z + bv.z, 0.f);
    float t3 = fmaxf(di * acc.w + bv.w, 0.f);
    float v0 = t0 * w0.x + t1 * w0.z + t2 * w1.x + t3 * w1.z;
    float v1 = t0 * w0.y + t1 * w0.w + t2 * w1.y + t3 * w1.w;
#pragma unroll
    for (int off = 1; off <= 8; off <<= 1) {   // sum the 16 feature classes
        v0 += __shfl_xor(v0, off, 64);
        v1 += __shfl_xor(v1, off, 64);
    }
    if (lane == 0) {
        h2s[(size_t)node * 2 + 0] = di * v0;
        h2s[(size_t)node * 2 + 1] = di * v1;
    }
}

// ---------- layer-2 gather, one thread per node ----------
__global__ void gather2_kernel(const int* __restrict__ rowstart,
                               const int* __restrict__ eidx, const float* __restrict__ dis,
                               const float* __restrict__ h2s, const float* __restrict__ b2,
                               float* __restrict__ out, int n) {
    int i = blockIdx.x * blockDim.x + threadIdx.x;
    if (i >= n) return;
    int rs = rowstart[i];
    int dn = rowstart[i + 1] - rs;
    float a0 = 0.f, a1 = 0.f, b0 = 0.f, b1v = 0.f;
    int j = 0;
    for (; j + 2 <= dn; j += 2) {
        int s0 = eidx[rs + j];
        int s1 = eidx[rs + j + 1];
        a0 += h2s[(size_t)s0 * 2 + 0];
        a1 += h2s[(size_t)s0 * 2 + 1];
        b0 += h2s[(size_t)s1 * 2 + 0];
        b1v += h2s[(size_t)s1 * 2 + 1];
    }
    if (j < dn) {
        int s0 = eidx[rs + j];
        a0 += h2s[(size_t)s0 * 2 + 0];
        a1 += h2s[(size_t)s0 * 2 + 1];
    }
    float di = dis[i];
    out[(size_t)i * 2 + 0] = di * (a0 + b0) + b2[0];
    out[(size_t)i * 2 + 1] = di * (a1 + b1v) + b2[1];
}

extern "C" void kernel_launch(void* const* d_in, const int* in_sizes, int n_in,
                              void* d_out, int out_size, void* d_ws, size_t ws_size,
                              hipStream_t stream) {
    const float* x  = (const float*)d_in[0];
    const int*   ei = (const int*)d_in[1];
    const float* W1 = (const float*)d_in[2];
    const float* b1 = (const float*)d_in[3];
    const float* W2 = (const float*)d_in[4];
    const float* b2 = (const float*)d_in[5];
    float* out = (float*)d_out;

    const int n = in_sizes[0] / 64;   // 100000
    const int e = in_sizes[1] / 2;    // 1600000
    const int* srcI = ei;
    const int* dstI = ei + e;

    // workspace layout (256-B aligned segments)
    char* p = (char*)d_ws;
    int* rowstart = (int*)p;    p += ((size_t)(n + 1) * 4 + 255) & ~255ull;
    float* dis    = (float*)p;  p += ((size_t)n * 4 + 255) & ~255ull;
    float* sums   = (float*)p;  p += 256;
    float* cvec   = (float*)p;  p += 256;
    int* cursor   = (int*)p;    p += 512;
    int* eidx     = (int*)p;    p += ((size_t)e * 4 + 255) & ~255ull;
    // union: pairs (9.4 MB packed) dead before gemm1 writes h1s (bf16, 12.8 MB)
    unsigned* pairs      = (unsigned*)p;
    unsigned short* h1s  = (unsigned short*)p;
    {
        size_t pairs_sz = (size_t)BKT * BKT_CAP * 4;
        size_t h1s_sz   = (size_t)n * 64 * 2;
        size_t u = pairs_sz > h1s_sz ? pairs_sz : h1s_sz;
        p += (u + 255) & ~255ull;
    }
    float* h2s    = (float*)p;

    hipMemsetAsync(cursor, 0, 512, stream);
    hipMemsetAsync(sums, 0, 256, stream);

    const int nchunks = (e + CHUNK - 1) / CHUNK;           // 782
    const int nbkt    = (n + NPB - 1) / NPB;               // 98

    colsum_kernel<<<1024, 256, 0, stream>>>(x, sums, (long long)n * 64);
    bucketA_kernel<<<nchunks, 256, 0, stream>>>(srcI, dstI, e, pairs, cursor);
    csrB_kernel<<<nbkt, 512, 0, stream>>>(pairs, cursor, dis, rowstart, eidx, n);
    cvec_kernel<<<1, 64, 0, stream>>>(sums, W1, cvec, n);
    gemm1_kernel<<<(n + 63) / 64, 256, 0, stream>>>(x, W1, cvec, dis, h1s, n);
    gather1_kernel<<<(n + 3) / 4, 256, 0, stream>>>(rowstart, eidx, dis, h1s, b1, W2, h2s, n);
    gather2_kernel<<<(n + 255) / 256, 256, 0, stream>>>(rowstart, eidx, dis, h2s, b2, out, n);
}

// Round 8
// 236.943 us; speedup vs baseline: 3.6777x; 2.7969x over previous
//
#include <hip/hip_runtime.h>

// GCN 2-layer, CSR-by-dst gather formulation; h1s in bf16. (R4 skeleton.)
// R7: gemm1 inner loop reverted to R4's measured-good form (scalar Xs reads,
// compiler re-vectorizes; manual b128 widening in R6 caused scratch spills ->
// 1.4 GB/dispatch HBM traffic). Pairs stay packed to 4 B (src<<10 | dst&1023).
// out = A_hat( relu( A_hat( [x|mean]@W1 ) + b1 ) @ W2 ) + b2
// Identity: [x|mean]@W1 = x@W1[:64] + c, c = mean@W1[64:].
// Pre-scaling: h1s[s] = dis[s]*(xW1+c)[s];  h2s[s] = dis[s]*(relu(.)@W2)[s].

#define BKT        128     // dst-range buckets
#define BKT_SHIFT  10      // 1024 nodes per bucket
#define NPB        1024
#define BKT_CAP    18432   // mean ~16327 + 16 sigma
#define CHUNK      2048    // edges per bucketA block
#define EPT        8       // edges per thread in bucketA

__device__ __forceinline__ unsigned short f2bf(float v) {
    unsigned u = __float_as_uint(v);
    u += 0x7FFFu + ((u >> 16) & 1u);   // round-to-nearest-even
    return (unsigned short)(u >> 16);
}
__device__ __forceinline__ float bf2f(unsigned short h) {
    return __uint_as_float((unsigned)h << 16);
}

// ---------- column sums of x (for mean) ----------
__global__ void colsum_kernel(const float* __restrict__ x, float* __restrict__ sums,
                              long long total) {
    int tid = threadIdx.x;
    long long g = (long long)blockIdx.x * blockDim.x + tid;
    long long stride = (long long)gridDim.x * blockDim.x;  // multiple of 64 -> column fixed
    float acc = 0.f;
    for (; g < total; g += stride) acc += x[g];
    __shared__ float s[256];
    s[tid] = acc;
    __syncthreads();
    if (tid < 64) {
        float v = s[tid] + s[tid + 64] + s[tid + 128] + s[tid + 192];
        atomicAdd(&sums[tid], v);
    }
}

// ---------- pass A: LDS multi-split; packed 4-B records (src<<10 | dst&1023) ----------
__global__ void bucketA_kernel(const int* __restrict__ src, const int* __restrict__ dst,
                               int e, unsigned* __restrict__ pairs, int* __restrict__ cursor) {
    __shared__ int cnt[BKT], sb[BKT], gpos[BKT];
    __shared__ unsigned stage[CHUNK];
    __shared__ unsigned char bb[CHUNK];
    int tid = threadIdx.x;
    int chunkStart = blockIdx.x * CHUNK;
    int v = e - chunkStart;
    if (v > CHUNK) v = CHUNK;
    if (tid < BKT) cnt[tid] = 0;
    __syncthreads();
    int myb[EPT], myoff[EPT];
    unsigned myp[EPT];
#pragma unroll
    for (int t = 0; t < EPT; ++t) {
        int i = chunkStart + t * 256 + tid;
        myb[t] = -1;
        if (i < e) {
            int s = src[i], d = dst[i];
            myb[t] = d >> BKT_SHIFT;
            myp[t] = ((unsigned)s << BKT_SHIFT) | (unsigned)(d & (NPB - 1));
            myoff[t] = atomicAdd(&cnt[myb[t]], 1);
        }
    }
    __syncthreads();
    if (tid < BKT) sb[tid] = cnt[tid];
    __syncthreads();
    for (int off = 1; off < BKT; off <<= 1) {
        int t = (tid < BKT && tid >= off) ? sb[tid - off] : 0;
        __syncthreads();
        if (tid < BKT) sb[tid] += t;
        __syncthreads();
    }
    if (tid < BKT) {
        int excl = tid ? sb[tid - 1] : 0;
        int gb = atomicAdd(&cursor[tid], cnt[tid]);
        gpos[tid] = tid * BKT_CAP + gb - excl;
        cnt[tid] = excl;  // reuse as stage base
    }
    __syncthreads();
#pragma unroll
    for (int t = 0; t < EPT; ++t) {
        if (myb[t] >= 0) {
            int p = cnt[myb[t]] + myoff[t];
            stage[p] = myp[t];
            bb[p] = (unsigned char)myb[t];
        }
    }
    __syncthreads();
    for (int j = tid; j < v; j += 256) {
        pairs[gpos[bb[j]] + j] = stage[j];  // contiguous runs per bucket
    }
}

// ---------- pass B: per-bucket hist + scan + ordered eidx fill; emits dis + rowstart ----------
__global__ void csrB_kernel(const unsigned* __restrict__ pairs, const int* __restrict__ cursor,
                            float* __restrict__ dis, int* __restrict__ rowstart,
                            int* __restrict__ eidx, int n) {
    __shared__ int ldeg[NPB];
    __shared__ int lcur[NPB];
    __shared__ int scanbuf[512];
    __shared__ int s_ebase;
    int b = blockIdx.x;
    int tid = threadIdx.x;
    int node0 = b << BKT_SHIFT;
    if (node0 >= n) return;
    int nl = n - node0;
    if (nl > NPB) nl = NPB;
    int cnt_b = cursor[b];
    for (int i = tid; i < NPB; i += 512) ldeg[i] = 0;
    if (tid == 0) {
        int s = 0;
        for (int q = 0; q < b; ++q) s += cursor[q];
        s_ebase = s;
    }
    __syncthreads();
    const unsigned* mp = pairs + (size_t)b * BKT_CAP;
    for (int i = tid; i < cnt_b; i += 512)
        atomicAdd(&ldeg[mp[i] & (NPB - 1)], 1);
    __syncthreads();
    int base = tid * 2;
    int ts = ldeg[base] + ldeg[base + 1];
    scanbuf[tid] = ts;
    __syncthreads();
    for (int off = 1; off < 512; off <<= 1) {
        int t = (tid >= off) ? scanbuf[tid - off] : 0;
        __syncthreads();
        scanbuf[tid] += t;
        __syncthreads();
    }
    int ex = tid ? scanbuf[tid - 1] : 0;
    int ebase = s_ebase;
#pragma unroll
    for (int j = 0; j < 2; ++j) {
        lcur[base + j] = ex;
        if (base + j < nl) {
            int dv = ldeg[base + j];
            rowstart[node0 + base + j] = ebase + ex;
            dis[node0 + base + j] = dv > 0 ? rsqrtf((float)dv) : 0.f;
        }
        ex += ldeg[base + j];
    }
    if (tid == 0 && node0 + NPB >= n)          // last bucket: close the CSR
        rowstart[n] = ebase + cnt_b;
    __syncthreads();
    for (int i = tid; i < cnt_b; i += 512) {
        unsigned p = mp[i];
        int pos = atomicAdd(&lcur[p & (NPB - 1)], 1);
        eidx[ebase + pos] = (int)(p >> BKT_SHIFT);  // contiguous ~65 KB window
    }
}

// ---------- c = mean @ W1[64:] ----------
__global__ void cvec_kernel(const float* __restrict__ sums, const float* __restrict__ W1,
                            float* __restrict__ c, int n) {
    int j = threadIdx.x;  // 64 threads
    float inv_n = 1.0f / (float)n;
    float acc = 0.f;
    for (int k = 0; k < 64; ++k) acc += (sums[k] * inv_n) * W1[(64 + k) * 64 + j];
    c[j] = acc;
}

// ---------- h1s(bf16) = dis[row] * (x @ W1[:64] + c); R4 inner loop ----------
__global__ __launch_bounds__(256, 4) void gemm1_kernel(
        const float* __restrict__ x, const float* __restrict__ W1,
        const float* __restrict__ c, const float* __restrict__ dis,
        unsigned short* __restrict__ h1s, int n) {
    __shared__ float Ws[64 * 64];   // [k][j]
    __shared__ float Xs[64 * 68];   // pad 68
    int tid = threadIdx.x;
    int row0 = blockIdx.x * 64;
    {
        const float4* w4 = (const float4*)W1;
        float4* s4 = (float4*)Ws;
        for (int i = tid; i < 1024; i += 256) s4[i] = w4[i];
    }
    for (int i = tid; i < 1024; i += 256) {
        int r = i >> 4, c4 = (i & 15) * 4;
        int gr = row0 + r;
        float4 xv = make_float4(0.f, 0.f, 0.f, 0.f);
        if (gr < n) xv = *(const float4*)&x[(size_t)gr * 64 + c4];
        *(float4*)&Xs[r * 68 + c4] = xv;
    }
    __syncthreads();
    int c16 = tid & 15;
    int rb = (tid >> 4) * 4;
    float4 cj = ((const float4*)c)[c16];
    float4 a0 = cj, a1 = cj, a2 = cj, a3 = cj;
#pragma unroll 4
    for (int k = 0; k < 64; ++k) {
        float4 w = *(const float4*)&Ws[k * 64 + c16 * 4];
        float x0 = Xs[(rb + 0) * 68 + k];
        float x1 = Xs[(rb + 1) * 68 + k];
        float x2 = Xs[(rb + 2) * 68 + k];
        float x3 = Xs[(rb + 3) * 68 + k];
        a0.x += x0 * w.x; a0.y += x0 * w.y; a0.z += x0 * w.z; a0.w += x0 * w.w;
        a1.x += x1 * w.x; a1.y += x1 * w.y; a1.z += x1 * w.z; a1.w += x1 * w.w;
        a2.x += x2 * w.x; a2.y += x2 * w.y; a2.z += x2 * w.z; a2.w += x2 * w.w;
        a3.x += x3 * w.x; a3.y += x3 * w.y; a3.z += x3 * w.z; a3.w += x3 * w.w;
    }
    float4 accs[4] = {a0, a1, a2, a3};
#pragma unroll
    for (int r = 0; r < 4; ++r) {
        int gr = row0 + rb + r;
        if (gr < n) {
            float dv = dis[gr];
            float4 o = accs[r];
            ushort4 hs;
            hs.x = f2bf(o.x * dv);
            hs.y = f2bf(o.y * dv);
            hs.z = f2bf(o.z * dv);
            hs.w = f2bf(o.w * dv);
            *(ushort4*)&h1s[(size_t)gr * 64 + c16 * 4] = hs;
        }
    }
}

// ---------- layer-1 gather: 16 lanes per edge, ushort4 per lane; one wave/node ----------
__global__ void gather1_kernel(const int* __restrict__ rowstart,
                               const int* __restrict__ eidx, const float* __restrict__ dis,
                               const unsigned short* __restrict__ h1s,
                               const float* __restrict__ b1, const float* __restrict__ W2,
                               float* __restrict__ h2s, int n) {
    int lane = threadIdx.x & 63;
    int node = blockIdx.x * 4 + (threadIdx.x >> 6);
    if (node >= n) return;
    int rs = rowstart[node];
    int re = rowstart[node + 1];
    int dn = re - rs;
    int m = dn < 64 ? dn : 64;
    int eHeld = (lane < m) ? eidx[rs + lane] : 0;  // one coalesced load for <=64 edges
    int g  = lane >> 4;        // edge subgroup 0..3
    int fb = (lane & 15) * 4;  // feature base
    float4 acc = make_float4(0.f, 0.f, 0.f, 0.f);
    int j = 0;
    for (; j + 8 <= m; j += 8) {           // 8 edges per iter, 2 loads in flight
        int sa = __shfl(eHeld, j + g, 64);
        int sb = __shfl(eHeld, j + 4 + g, 64);
        ushort4 ha = *(const ushort4*)&h1s[((size_t)sa << 6) + fb];
        ushort4 hb = *(const ushort4*)&h1s[((size_t)sb << 6) + fb];
        acc.x += bf2f(ha.x) + bf2f(hb.x);
        acc.y += bf2f(ha.y) + bf2f(hb.y);
        acc.z += bf2f(ha.z) + bf2f(hb.z);
        acc.w += bf2f(ha.w) + bf2f(hb.w);
    }
    for (; j < m; j += 4) {                // ragged tail, 0..2 iters
        int jj = j + g;
        int s = __shfl(eHeld, jj < m ? jj : 0, 64);
        if (jj < m) {
            ushort4 h = *(const ushort4*)&h1s[((size_t)s << 6) + fb];
            acc.x += bf2f(h.x);
            acc.y += bf2f(h.y);
            acc.z += bf2f(h.z);
            acc.w += bf2f(h.w);
        }
    }
    for (int t = 64; t < dn; ++t) {        // deg > 64: astronomically rare here
        if (g == 0) {
            int s = eidx[rs + t];
            ushort4 h = *(const ushort4*)&h1s[((size_t)s << 6) + fb];
            acc.x += bf2f(h.x);
            acc.y += bf2f(h.y);
            acc.z += bf2f(h.z);
            acc.w += bf2f(h.w);
        }
    }
    // reduce across the 4 edge subgroups
    acc.x += __shfl_xor(acc.x, 16, 64); acc.x += __shfl_xor(acc.x, 32, 64);
    acc.y += __shfl_xor(acc.y, 16, 64); acc.y += __shfl_xor(acc.y, 32, 64);
    acc.z += __shfl_xor(acc.z, 16, 64); acc.z += __shfl_xor(acc.z, 32, 64);
    acc.w += __shfl_xor(acc.w, 16, 64); acc.w += __shfl_xor(acc.w, 32, 64);
    float di = dis[node];
    float4 bv = ((const float4*)b1)[lane & 15];
    float4 w0 = ((const float4*)W2)[(lane & 15) * 2];
    float4 w1 = ((const float4*)W2)[(lane & 15) * 2 + 1];
    float t0 = fmaxf(di * acc.x + bv.x, 0.f);
    float t1 = fmaxf(di * acc.y + bv.y, 0.f);
    float t2 = fmaxf(di * acc.z + bv.z, 0.f);
    float t3 = fmaxf(di * acc.w + bv.w, 0.f);
    float v0 = t0 * w0.x + t1 * w0.z + t2 * w1.x + t3 * w1.z;
    float v1 = t0 * w0.y + t1 * w0.w + t2 * w1.y + t3 * w1.w;
#pragma unroll
    for (int off = 1; off <= 8; off <<= 1) {   // sum the 16 feature classes
        v0 += __shfl_xor(v0, off, 64);
        v1 += __shfl_xor(v1, off, 64);
    }
    if (lane == 0) {
        h2s[(size_t)node * 2 + 0] = di * v0;
        h2s[(size_t)node * 2 + 1] = di * v1;
    }
}

// ---------- layer-2 gather, one thread per node ----------
__global__ void gather2_kernel(const int* __restrict__ rowstart,
                               const int* __restrict__ eidx, const float* __restrict__ dis,
                               const float* __restrict__ h2s, const float* __restrict__ b2,
                               float* __restrict__ out, int n) {
    int i = blockIdx.x * blockDim.x + threadIdx.x;
    if (i >= n) return;
    int rs = rowstart[i];
    int dn = rowstart[i + 1] - rs;
    float a0 = 0.f, a1 = 0.f, b0 = 0.f, b1v = 0.f;
    int j = 0;
    for (; j + 2 <= dn; j += 2) {
        int s0 = eidx[rs + j];
        int s1 = eidx[rs + j + 1];
        a0 += h2s[(size_t)s0 * 2 + 0];
        a1 += h2s[(size_t)s0 * 2 + 1];
        b0 += h2s[(size_t)s1 * 2 + 0];
        b1v += h2s[(size_t)s1 * 2 + 1];
    }
    if (j < dn) {
        int s0 = eidx[rs + j];
        a0 += h2s[(size_t)s0 * 2 + 0];
        a1 += h2s[(size_t)s0 * 2 + 1];
    }
    float di = dis[i];
    out[(size_t)i * 2 + 0] = di * (a0 + b0) + b2[0];
    out[(size_t)i * 2 + 1] = di * (a1 + b1v) + b2[1];
}

extern "C" void kernel_launch(void* const* d_in, const int* in_sizes, int n_in,
                              void* d_out, int out_size, void* d_ws, size_t ws_size,
                              hipStream_t stream) {
    const float* x  = (const float*)d_in[0];
    const int*   ei = (const int*)d_in[1];
    const float* W1 = (const float*)d_in[2];
    const float* b1 = (const float*)d_in[3];
    const float* W2 = (const float*)d_in[4];
    const float* b2 = (const float*)d_in[5];
    float* out = (float*)d_out;

    const int n = in_sizes[0] / 64;   // 100000
    const int e = in_sizes[1] / 2;    // 1600000
    const int* srcI = ei;
    const int* dstI = ei + e;

    // workspace layout (256-B aligned segments)
    char* p = (char*)d_ws;
    int* rowstart = (int*)p;    p += ((size_t)(n + 1) * 4 + 255) & ~255ull;
    float* dis    = (float*)p;  p += ((size_t)n * 4 + 255) & ~255ull;
    float* sums   = (float*)p;  p += 256;
    float* cvec   = (float*)p;  p += 256;
    int* cursor   = (int*)p;    p += 512;
    int* eidx     = (int*)p;    p += ((size_t)e * 4 + 255) & ~255ull;
    // union: pairs (9.4 MB packed) dead before gemm1 writes h1s (bf16, 12.8 MB)
    unsigned* pairs      = (unsigned*)p;
    unsigned short* h1s  = (unsigned short*)p;
    {
        size_t pairs_sz = (size_t)BKT * BKT_CAP * 4;
        size_t h1s_sz   = (size_t)n * 64 * 2;
        size_t u = pairs_sz > h1s_sz ? pairs_sz : h1s_sz;
        p += (u + 255) & ~255ull;
    }
    float* h2s    = (float*)p;

    hipMemsetAsync(cursor, 0, 512, stream);
    hipMemsetAsync(sums, 0, 256, stream);

    const int nchunks = (e + CHUNK - 1) / CHUNK;           // 782
    const int nbkt    = (n + NPB - 1) / NPB;               // 98

    colsum_kernel<<<1024, 256, 0, stream>>>(x, sums, (long long)n * 64);
    bucketA_kernel<<<nchunks, 256, 0, stream>>>(srcI, dstI, e, pairs, cursor);
    csrB_kernel<<<nbkt, 512, 0, stream>>>(pairs, cursor, dis, rowstart, eidx, n);
    cvec_kernel<<<1, 64, 0, stream>>>(sums, W1, cvec, n);
    gemm1_kernel<<<(n + 63) / 64, 256, 0, stream>>>(x, W1, cvec, dis, h1s, n);
    gather1_kernel<<<(n + 3) / 4, 256, 0, stream>>>(rowstart, eidx, dis, h1s, b1, W2, h2s, n);
    gather2_kernel<<<(n + 255) / 256, 256, 0, stream>>>(rowstart, eidx, dis, h2s, b2, out, n);
}

// Round 9
// 219.768 us; speedup vs baseline: 3.9651x; 1.0782x over previous
//
#include <hip/hip_runtime.h>

// GCN 2-layer, CSR-by-dst gather formulation; h1s in bf16.
// R8: 6 dispatches (memset, bucketA+colsum, csrB+cvec, gemm1, gather1, gather2)
//     — launch-gap overhead (~10us/dispatch) was ~40% of runtime.
//     gather1: 16 edges/iter, 4 independent loads in flight (deg~Pois(16)).
// out = A_hat( relu( A_hat( [x|mean]@W1 ) + b1 ) @ W2 ) + b2
// Identity: [x|mean]@W1 = x@W1[:64] + c, c = mean@W1[64:].
// Pre-scaling: h1s[s] = dis[s]*(xW1+c)[s];  h2s[s] = dis[s]*(relu(.)@W2)[s].

#define BKT        128     // dst-range buckets
#define BKT_SHIFT  10      // 1024 nodes per bucket
#define NPB        1024
#define BKT_CAP    18432   // mean ~16327 + 16 sigma
#define CHUNK      2048    // edges per bucketA block
#define EPT        8       // edges per thread in bucketA
#define CS_BLK     64      // colsum blocks appended to bucketA grid

__device__ __forceinline__ unsigned short f2bf(float v) {
    unsigned u = __float_as_uint(v);
    u += 0x7FFFu + ((u >> 16) & 1u);   // round-to-nearest-even
    return (unsigned short)(u >> 16);
}
__device__ __forceinline__ float bf2f(unsigned short h) {
    return __uint_as_float((unsigned)h << 16);
}

// ---------- pass A: LDS multi-split (blocks < nchunks) + colsum (last 64 blocks) ----------
__global__ void bucketAC_kernel(const int* __restrict__ src, const int* __restrict__ dst,
                                int e, int nchunks, unsigned* __restrict__ pairs,
                                int* __restrict__ cursor,
                                const float* __restrict__ x, float* __restrict__ sums, int n) {
    int tid = threadIdx.x;
    if (blockIdx.x >= nchunks) {
        // ---- colsum side-job: column sums of x via float4 grid-stride ----
        __shared__ float4 s4[256];
        int cb = blockIdx.x - nchunks;           // 0..CS_BLK-1
        const float4* x4 = (const float4*)x;
        int total4 = n * 16;
        float4 acc = make_float4(0.f, 0.f, 0.f, 0.f);
        // stride CS_BLK*256 = 16384 float4 == 0 mod 16 -> col group (i&15) fixed
        for (int i = cb * 256 + tid; i < total4; i += CS_BLK * 256) {
            float4 v = x4[i];
            acc.x += v.x; acc.y += v.y; acc.z += v.z; acc.w += v.w;
        }
        s4[tid] = acc;
        __syncthreads();
        if (tid < 16) {
            float4 v = s4[tid];
            for (int k = 1; k < 16; ++k) {
                float4 w = s4[tid + 16 * k];
                v.x += w.x; v.y += w.y; v.z += w.z; v.w += w.w;
            }
            atomicAdd(&sums[tid * 4 + 0], v.x);
            atomicAdd(&sums[tid * 4 + 1], v.y);
            atomicAdd(&sums[tid * 4 + 2], v.z);
            atomicAdd(&sums[tid * 4 + 3], v.w);
        }
        return;
    }
    // ---- bucket multi-split: packed 4-B records (src<<10 | dst&1023) ----
    __shared__ int cnt[BKT], sb[BKT], gpos[BKT];
    __shared__ unsigned stage[CHUNK];
    __shared__ unsigned char bb[CHUNK];
    int chunkStart = blockIdx.x * CHUNK;
    int v = e - chunkStart;
    if (v > CHUNK) v = CHUNK;
    if (tid < BKT) cnt[tid] = 0;
    __syncthreads();
    int myb[EPT], myoff[EPT];
    unsigned myp[EPT];
#pragma unroll
    for (int t = 0; t < EPT; ++t) {
        int i = chunkStart + t * 256 + tid;
        myb[t] = -1;
        if (i < e) {
            int s = src[i], d = dst[i];
            myb[t] = d >> BKT_SHIFT;
            myp[t] = ((unsigned)s << BKT_SHIFT) | (unsigned)(d & (NPB - 1));
            myoff[t] = atomicAdd(&cnt[myb[t]], 1);
        }
    }
    __syncthreads();
    if (tid < BKT) sb[tid] = cnt[tid];
    __syncthreads();
    for (int off = 1; off < BKT; off <<= 1) {
        int t = (tid < BKT && tid >= off) ? sb[tid - off] : 0;
        __syncthreads();
        if (tid < BKT) sb[tid] += t;
        __syncthreads();
    }
    if (tid < BKT) {
        int excl = tid ? sb[tid - 1] : 0;
        int gb = atomicAdd(&cursor[tid], cnt[tid]);
        gpos[tid] = tid * BKT_CAP + gb - excl;
        cnt[tid] = excl;  // reuse as stage base
    }
    __syncthreads();
#pragma unroll
    for (int t = 0; t < EPT; ++t) {
        if (myb[t] >= 0) {
            int p = cnt[myb[t]] + myoff[t];
            stage[p] = myp[t];
            bb[p] = (unsigned char)myb[t];
        }
    }
    __syncthreads();
    for (int j = tid; j < v; j += 256) {
        pairs[gpos[bb[j]] + j] = stage[j];  // contiguous runs per bucket
    }
}

// ---------- pass B: per-bucket hist+scan+fill; emits dis+rowstart; block0: cvec ----------
__global__ void csrB_kernel(const unsigned* __restrict__ pairs, const int* __restrict__ cursor,
                            float* __restrict__ dis, int* __restrict__ rowstart,
                            int* __restrict__ eidx, int n,
                            const float* __restrict__ sums, const float* __restrict__ W1,
                            float* __restrict__ cvec) {
    __shared__ int ldeg[NPB];
    __shared__ int lcur[NPB];
    __shared__ int scanbuf[512];
    __shared__ int s_ebase;
    int b = blockIdx.x;
    int tid = threadIdx.x;
    int node0 = b << BKT_SHIFT;
    if (node0 >= n) return;
    int nl = n - node0;
    if (nl > NPB) nl = NPB;
    int cnt_b = cursor[b];
    for (int i = tid; i < NPB; i += 512) ldeg[i] = 0;
    if (tid == 0) {
        int s = 0;
        for (int q = 0; q < b; ++q) s += cursor[q];
        s_ebase = s;
    }
    __syncthreads();
    const unsigned* mp = pairs + (size_t)b * BKT_CAP;
    for (int i = tid; i < cnt_b; i += 512)
        atomicAdd(&ldeg[mp[i] & (NPB - 1)], 1);
    __syncthreads();
    int base = tid * 2;
    int ts = ldeg[base] + ldeg[base + 1];
    scanbuf[tid] = ts;
    __syncthreads();
    for (int off = 1; off < 512; off <<= 1) {
        int t = (tid >= off) ? scanbuf[tid - off] : 0;
        __syncthreads();
        scanbuf[tid] += t;
        __syncthreads();
    }
    int ex = tid ? scanbuf[tid - 1] : 0;
    int ebase = s_ebase;
#pragma unroll
    for (int j = 0; j < 2; ++j) {
        lcur[base + j] = ex;
        if (base + j < nl) {
            int dv = ldeg[base + j];
            rowstart[node0 + base + j] = ebase + ex;
            dis[node0 + base + j] = dv > 0 ? rsqrtf((float)dv) : 0.f;
        }
        ex += ldeg[base + j];
    }
    if (tid == 0 && node0 + NPB >= n)          // last bucket: close the CSR
        rowstart[n] = ebase + cnt_b;
    __syncthreads();
    for (int i = tid; i < cnt_b; i += 512) {
        unsigned p = mp[i];
        int pos = atomicAdd(&lcur[p & (NPB - 1)], 1);
        eidx[ebase + pos] = (int)(p >> BKT_SHIFT);  // contiguous ~65 KB window
    }
    // ---- cvec side-job (block 0 only; ready before gemm1 launches) ----
    if (b == 0 && tid < 64) {
        float inv_n = 1.0f / (float)n;
        float acc = 0.f;
        for (int k = 0; k < 64; ++k) acc += (sums[k] * inv_n) * W1[(64 + k) * 64 + tid];
        cvec[tid] = acc;
    }
}

// ---------- h1s(bf16) = dis[row] * (x @ W1[:64] + c); measured-good inner loop ----------
__global__ __launch_bounds__(256, 4) void gemm1_kernel(
        const float* __restrict__ x, const float* __restrict__ W1,
        const float* __restrict__ c, const float* __restrict__ dis,
        unsigned short* __restrict__ h1s, int n) {
    __shared__ float Ws[64 * 64];   // [k][j]
    __shared__ float Xs[64 * 68];   // pad 68
    int tid = threadIdx.x;
    int row0 = blockIdx.x * 64;
    {
        const float4* w4 = (const float4*)W1;
        float4* s4 = (float4*)Ws;
        for (int i = tid; i < 1024; i += 256) s4[i] = w4[i];
    }
    for (int i = tid; i < 1024; i += 256) {
        int r = i >> 4, c4 = (i & 15) * 4;
        int gr = row0 + r;
        float4 xv = make_float4(0.f, 0.f, 0.f, 0.f);
        if (gr < n) xv = *(const float4*)&x[(size_t)gr * 64 + c4];
        *(float4*)&Xs[r * 68 + c4] = xv;
    }
    __syncthreads();
    int c16 = tid & 15;
    int rb = (tid >> 4) * 4;
    float4 cj = ((const float4*)c)[c16];
    float4 a0 = cj, a1 = cj, a2 = cj, a3 = cj;
#pragma unroll 4
    for (int k = 0; k < 64; ++k) {
        float4 w = *(const float4*)&Ws[k * 64 + c16 * 4];
        float x0 = Xs[(rb + 0) * 68 + k];
        float x1 = Xs[(rb + 1) * 68 + k];
        float x2 = Xs[(rb + 2) * 68 + k];
        float x3 = Xs[(rb + 3) * 68 + k];
        a0.x += x0 * w.x; a0.y += x0 * w.y; a0.z += x0 * w.z; a0.w += x0 * w.w;
        a1.x += x1 * w.x; a1.y += x1 * w.y; a1.z += x1 * w.z; a1.w += x1 * w.w;
        a2.x += x2 * w.x; a2.y += x2 * w.y; a2.z += x2 * w.z; a2.w += x2 * w.w;
        a3.x += x3 * w.x; a3.y += x3 * w.y; a3.z += x3 * w.z; a3.w += x3 * w.w;
    }
    float4 accs[4] = {a0, a1, a2, a3};
#pragma unroll
    for (int r = 0; r < 4; ++r) {
        int gr = row0 + rb + r;
        if (gr < n) {
            float dv = dis[gr];
            float4 o = accs[r];
            ushort4 hs;
            hs.x = f2bf(o.x * dv);
            hs.y = f2bf(o.y * dv);
            hs.z = f2bf(o.z * dv);
            hs.w = f2bf(o.w * dv);
            *(ushort4*)&h1s[(size_t)gr * 64 + c16 * 4] = hs;
        }
    }
}

// ---------- layer-1 gather: 16 lanes/edge, 16 edges/iter (4 loads in flight) ----------
__global__ void gather1_kernel(const int* __restrict__ rowstart,
                               const int* __restrict__ eidx, const float* __restrict__ dis,
                               const unsigned short* __restrict__ h1s,
                               const float* __restrict__ b1, const float* __restrict__ W2,
                               float* __restrict__ h2s, int n) {
    int lane = threadIdx.x & 63;
    int node = blockIdx.x * 4 + (threadIdx.x >> 6);
    if (node >= n) return;
    int rs = rowstart[node];
    int re = rowstart[node + 1];
    int dn = re - rs;
    int m = dn < 64 ? dn : 64;
    int eHeld = (lane < m) ? eidx[rs + lane] : 0;  // one coalesced load for <=64 edges
    int g  = lane >> 4;        // edge subgroup 0..3
    int fb = (lane & 15) * 4;  // feature base
    float4 acc = make_float4(0.f, 0.f, 0.f, 0.f);
    int j = 0;
    for (; j + 16 <= m; j += 16) {         // 16 edges per iter, 4 loads in flight
        int s0 = __shfl(eHeld, j + g, 64);
        int s1 = __shfl(eHeld, j + 4 + g, 64);
        int s2 = __shfl(eHeld, j + 8 + g, 64);
        int s3 = __shfl(eHeld, j + 12 + g, 64);
        ushort4 h0 = *(const ushort4*)&h1s[((size_t)s0 << 6) + fb];
        ushort4 h1 = *(const ushort4*)&h1s[((size_t)s1 << 6) + fb];
        ushort4 h2 = *(const ushort4*)&h1s[((size_t)s2 << 6) + fb];
        ushort4 h3 = *(const ushort4*)&h1s[((size_t)s3 << 6) + fb];
        acc.x += (bf2f(h0.x) + bf2f(h1.x)) + (bf2f(h2.x) + bf2f(h3.x));
        acc.y += (bf2f(h0.y) + bf2f(h1.y)) + (bf2f(h2.y) + bf2f(h3.y));
        acc.z += (bf2f(h0.z) + bf2f(h1.z)) + (bf2f(h2.z) + bf2f(h3.z));
        acc.w += (bf2f(h0.w) + bf2f(h1.w)) + (bf2f(h2.w) + bf2f(h3.w));
    }
    for (; j + 8 <= m; j += 8) {           // 8-edge tail, 2 loads
        int s0 = __shfl(eHeld, j + g, 64);
        int s1 = __shfl(eHeld, j + 4 + g, 64);
        ushort4 h0 = *(const ushort4*)&h1s[((size_t)s0 << 6) + fb];
        ushort4 h1 = *(const ushort4*)&h1s[((size_t)s1 << 6) + fb];
        acc.x += bf2f(h0.x) + bf2f(h1.x);
        acc.y += bf2f(h0.y) + bf2f(h1.y);
        acc.z += bf2f(h0.z) + bf2f(h1.z);
        acc.w += bf2f(h0.w) + bf2f(h1.w);
    }
    for (; j < m; j += 4) {                // ragged tail, 0..1 iters
        int jj = j + g;
        int s = __shfl(eHeld, jj < m ? jj : 0, 64);
        if (jj < m) {
            ushort4 h = *(const ushort4*)&h1s[((size_t)s << 6) + fb];
            acc.x += bf2f(h.x);
            acc.y += bf2f(h.y);
            acc.z += bf2f(h.z);
            acc.w += bf2f(h.w);
        }
    }
    for (int t = 64; t < dn; ++t) {        // deg > 64: astronomically rare here
        if (g == 0) {
            int s = eidx[rs + t];
            ushort4 h = *(const ushort4*)&h1s[((size_t)s << 6) + fb];
            acc.x += bf2f(h.x);
            acc.y += bf2f(h.y);
            acc.z += bf2f(h.z);
            acc.w += bf2f(h.w);
        }
    }
    // reduce across the 4 edge subgroups
    acc.x += __shfl_xor(acc.x, 16, 64); acc.x += __shfl_xor(acc.x, 32, 64);
    acc.y += __shfl_xor(acc.y, 16, 64); acc.y += __shfl_xor(acc.y, 32, 64);
    acc.z += __shfl_xor(acc.z, 16, 64); acc.z += __shfl_xor(acc.z, 32, 64);
    acc.w += __shfl_xor(acc.w, 16, 64); acc.w += __shfl_xor(acc.w, 32, 64);
    float di = dis[node];
    float4 bv = ((const float4*)b1)[lane & 15];
    float4 w0 = ((const float4*)W2)[(lane & 15) * 2];
    float4 w1 = ((const float4*)W2)[(lane & 15) * 2 + 1];
    float t0 = fmaxf(di * acc.x + bv.x, 0.f);
    float t1 = fmaxf(di * acc.y + bv.y, 0.f);
    float t2 = fmaxf(di * acc.z + bv.z, 0.f);
    float t3 = fmaxf(di * acc.w + bv.w, 0.f);
    float v0 = t0 * w0.x + t1 * w0.z + t2 * w1.x + t3 * w1.z;
    float v1 = t0 * w0.y + t1 * w0.w + t2 * w1.y + t3 * w1.w;
#pragma unroll
    for (int off = 1; off <= 8; off <<= 1) {   // sum the 16 feature classes
        v0 += __shfl_xor(v0, off, 64);
        v1 += __shfl_xor(v1, off, 64);
    }
    if (lane == 0) {
        h2s[(size_t)node * 2 + 0] = di * v0;
        h2s[(size_t)node * 2 + 1] = di * v1;
    }
}

// ---------- layer-2 gather, one thread per node ----------
__global__ void gather2_kernel(const int* __restrict__ rowstart,
                               const int* __restrict__ eidx, const float* __restrict__ dis,
                               const float* __restrict__ h2s, const float* __restrict__ b2,
                               float* __restrict__ out, int n) {
    int i = blockIdx.x * blockDim.x + threadIdx.x;
    if (i >= n) return;
    int rs = rowstart[i];
    int dn = rowstart[i + 1] - rs;
    float a0 = 0.f, a1 = 0.f, b0 = 0.f, b1v = 0.f;
    int j = 0;
    for (; j + 2 <= dn; j += 2) {
        int s0 = eidx[rs + j];
        int s1 = eidx[rs + j + 1];
        a0 += h2s[(size_t)s0 * 2 + 0];
        a1 += h2s[(size_t)s0 * 2 + 1];
        b0 += h2s[(size_t)s1 * 2 + 0];
        b1v += h2s[(size_t)s1 * 2 + 1];
    }
    if (j < dn) {
        int s0 = eidx[rs + j];
        a0 += h2s[(size_t)s0 * 2 + 0];
        a1 += h2s[(size_t)s0 * 2 + 1];
    }
    float di = dis[i];
    out[(size_t)i * 2 + 0] = di * (a0 + b0) + b2[0];
    out[(size_t)i * 2 + 1] = di * (a1 + b1v) + b2[1];
}

extern "C" void kernel_launch(void* const* d_in, const int* in_sizes, int n_in,
                              void* d_out, int out_size, void* d_ws, size_t ws_size,
                              hipStream_t stream) {
    const float* x  = (const float*)d_in[0];
    const int*   ei = (const int*)d_in[1];
    const float* W1 = (const float*)d_in[2];
    const float* b1 = (const float*)d_in[3];
    const float* W2 = (const float*)d_in[4];
    const float* b2 = (const float*)d_in[5];
    float* out = (float*)d_out;

    const int n = in_sizes[0] / 64;   // 100000
    const int e = in_sizes[1] / 2;    // 1600000
    const int* srcI = ei;
    const int* dstI = ei + e;

    // workspace layout (256-B aligned segments); sums+cursor adjacent -> 1 memset
    char* p = (char*)d_ws;
    int* rowstart = (int*)p;    p += ((size_t)(n + 1) * 4 + 255) & ~255ull;
    float* dis    = (float*)p;  p += ((size_t)n * 4 + 255) & ~255ull;
    float* sums   = (float*)p;              // 256 B
    int* cursor   = (int*)(p + 256);        // 512 B (BKT*4)
    char* zbase   = p;          p += 1024;  // single 1024-B memset region
    float* cvec   = (float*)p;  p += 256;
    int* eidx     = (int*)p;    p += ((size_t)e * 4 + 255) & ~255ull;
    // union: pairs (9.4 MB packed) dead before gemm1 writes h1s (bf16, 12.8 MB)
    unsigned* pairs      = (unsigned*)p;
    unsigned short* h1s  = (unsigned short*)p;
    {
        size_t pairs_sz = (size_t)BKT * BKT_CAP * 4;
        size_t h1s_sz   = (size_t)n * 64 * 2;
        size_t u = pairs_sz > h1s_sz ? pairs_sz : h1s_sz;
        p += (u + 255) & ~255ull;
    }
    float* h2s    = (float*)p;

    hipMemsetAsync(zbase, 0, 1024, stream);

    const int nchunks = (e + CHUNK - 1) / CHUNK;           // 782
    const int nbkt    = (n + NPB - 1) / NPB;               // 98

    bucketAC_kernel<<<nchunks + CS_BLK, 256, 0, stream>>>(srcI, dstI, e, nchunks,
                                                          pairs, cursor, x, sums, n);
    csrB_kernel<<<nbkt, 512, 0, stream>>>(pairs, cursor, dis, rowstart, eidx, n,
                                          sums, W1, cvec);
    gemm1_kernel<<<(n + 63) / 64, 256, 0, stream>>>(x, W1, cvec, dis, h1s, n);
    gather1_kernel<<<(n + 3) / 4, 256, 0, stream>>>(rowstart, eidx, dis, h1s, b1, W2, h2s, n);
    gather2_kernel<<<(n + 255) / 256, 256, 0, stream>>>(rowstart, eidx, dis, h2s, b2, out, n);
}

// Round 10
// 200.730 us; speedup vs baseline: 4.3412x; 1.0948x over previous
//
#include <hip/hip_runtime.h>

// GCN 2-layer, CSR-by-dst gather formulation; h1s in bf16.
// R9: bucketAC: colsum blocks FIRST (no serial tail); cursor padded to one
//     128-B line per bucket (global atomic contention 128x down); CHUNK 4096
//     with 512 threads (half the scan/atomic overhead per edge).
// out = A_hat( relu( A_hat( [x|mean]@W1 ) + b1 ) @ W2 ) + b2
// Identity: [x|mean]@W1 = x@W1[:64] + c, c = mean@W1[64:].
// Pre-scaling: h1s[s] = dis[s]*(xW1+c)[s];  h2s[s] = dis[s]*(relu(.)@W2)[s].

#define BKT        128     // dst-range buckets
#define BKT_SHIFT  10      // 1024 nodes per bucket
#define NPB        1024
#define BKT_CAP    18432   // mean ~12500 + >50 sigma
#define CHUNK      4096    // edges per bucketA block
#define EPT        8       // CHUNK / 512 threads
#define CS_BLK     64      // colsum blocks prepended to bucketA grid
#define CUR_STRIDE 32      // ints per cursor slot (128-B line each)

__device__ __forceinline__ unsigned short f2bf(float v) {
    unsigned u = __float_as_uint(v);
    u += 0x7FFFu + ((u >> 16) & 1u);   // round-to-nearest-even
    return (unsigned short)(u >> 16);
}
__device__ __forceinline__ float bf2f(unsigned short h) {
    return __uint_as_float((unsigned)h << 16);
}

// ---------- pass A: colsum (blocks 0..63) + LDS multi-split (remaining blocks) ----------
__global__ __launch_bounds__(512) void bucketAC_kernel(
        const int* __restrict__ src, const int* __restrict__ dst,
        int e, unsigned* __restrict__ pairs, int* __restrict__ cursor,
        const float* __restrict__ x, float* __restrict__ sums, int n) {
    int tid = threadIdx.x;
    if (blockIdx.x < CS_BLK) {
        // ---- colsum side-job: column sums of x via float4 grid-stride ----
        __shared__ float4 s4[512];
        int cb = blockIdx.x;                     // 0..CS_BLK-1
        const float4* x4 = (const float4*)x;
        int total4 = n * 16;
        float4 acc = make_float4(0.f, 0.f, 0.f, 0.f);
        // stride CS_BLK*512 = 32768 float4 == 0 mod 16 -> col group (i&15) fixed
        for (int i = cb * 512 + tid; i < total4; i += CS_BLK * 512) {
            float4 v = x4[i];
            acc.x += v.x; acc.y += v.y; acc.z += v.z; acc.w += v.w;
        }
        s4[tid] = acc;
        __syncthreads();
        if (tid < 16) {
            float4 v = s4[tid];
            for (int k = 1; k < 32; ++k) {
                float4 w = s4[tid + 16 * k];
                v.x += w.x; v.y += w.y; v.z += w.z; v.w += w.w;
            }
            atomicAdd(&sums[tid * 4 + 0], v.x);
            atomicAdd(&sums[tid * 4 + 1], v.y);
            atomicAdd(&sums[tid * 4 + 2], v.z);
            atomicAdd(&sums[tid * 4 + 3], v.w);
        }
        return;
    }
    // ---- bucket multi-split: packed 4-B records (src<<10 | dst&1023) ----
    __shared__ int cnt[BKT], sb[BKT], gpos[BKT];
    __shared__ unsigned stage[CHUNK];
    __shared__ unsigned char bb[CHUNK];
    int chunkStart = (blockIdx.x - CS_BLK) * CHUNK;
    int v = e - chunkStart;
    if (v > CHUNK) v = CHUNK;
    if (tid < BKT) cnt[tid] = 0;
    __syncthreads();
    int myb[EPT], myoff[EPT];
    unsigned myp[EPT];
#pragma unroll
    for (int t = 0; t < EPT; ++t) {
        int i = chunkStart + t * 512 + tid;
        myb[t] = -1;
        if (i < e) {
            int s = src[i], d = dst[i];
            myb[t] = d >> BKT_SHIFT;
            myp[t] = ((unsigned)s << BKT_SHIFT) | (unsigned)(d & (NPB - 1));
            myoff[t] = atomicAdd(&cnt[myb[t]], 1);
        }
    }
    __syncthreads();
    if (tid < BKT) sb[tid] = cnt[tid];
    __syncthreads();
    for (int off = 1; off < BKT; off <<= 1) {
        int t = (tid < BKT && tid >= off) ? sb[tid - off] : 0;
        __syncthreads();
        if (tid < BKT) sb[tid] += t;
        __syncthreads();
    }
    if (tid < BKT) {
        int excl = tid ? sb[tid - 1] : 0;
        int gb = atomicAdd(&cursor[tid * CUR_STRIDE], cnt[tid]);  // private line
        gpos[tid] = tid * BKT_CAP + gb - excl;
        cnt[tid] = excl;  // reuse as stage base
    }
    __syncthreads();
#pragma unroll
    for (int t = 0; t < EPT; ++t) {
        if (myb[t] >= 0) {
            int p = cnt[myb[t]] + myoff[t];
            stage[p] = myp[t];
            bb[p] = (unsigned char)myb[t];
        }
    }
    __syncthreads();
    for (int j = tid; j < v; j += 512) {
        pairs[gpos[bb[j]] + j] = stage[j];  // contiguous runs per bucket
    }
}

// ---------- pass B: per-bucket hist+scan+fill; emits dis+rowstart; block0: cvec ----------
__global__ __launch_bounds__(512) void csrB_kernel(
        const unsigned* __restrict__ pairs, const int* __restrict__ cursor,
        float* __restrict__ dis, int* __restrict__ rowstart,
        int* __restrict__ eidx, int n,
        const float* __restrict__ sums, const float* __restrict__ W1,
        float* __restrict__ cvec) {
    __shared__ int ldeg[NPB];
    __shared__ int lcur[NPB];
    __shared__ int scanbuf[512];
    __shared__ int s_ebase;
    int b = blockIdx.x;
    int tid = threadIdx.x;
    int node0 = b << BKT_SHIFT;
    if (node0 >= n) return;
    int nl = n - node0;
    if (nl > NPB) nl = NPB;
    int cnt_b = cursor[b * CUR_STRIDE];
    for (int i = tid; i < NPB; i += 512) ldeg[i] = 0;
    if (tid == 0) s_ebase = 0;
    __syncthreads();
    if (tid < b) atomicAdd(&s_ebase, cursor[tid * CUR_STRIDE]);  // parallel prefix
    const unsigned* mp = pairs + (size_t)b * BKT_CAP;
    for (int i = tid; i < cnt_b; i += 512)
        atomicAdd(&ldeg[mp[i] & (NPB - 1)], 1);
    __syncthreads();
    int base = tid * 2;
    int ts = ldeg[base] + ldeg[base + 1];
    scanbuf[tid] = ts;
    __syncthreads();
    for (int off = 1; off < 512; off <<= 1) {
        int t = (tid >= off) ? scanbuf[tid - off] : 0;
        __syncthreads();
        scanbuf[tid] += t;
        __syncthreads();
    }
    int ex = tid ? scanbuf[tid - 1] : 0;
    int ebase = s_ebase;
#pragma unroll
    for (int j = 0; j < 2; ++j) {
        lcur[base + j] = ex;
        if (base + j < nl) {
            int dv = ldeg[base + j];
            rowstart[node0 + base + j] = ebase + ex;
            dis[node0 + base + j] = dv > 0 ? rsqrtf((float)dv) : 0.f;
        }
        ex += ldeg[base + j];
    }
    if (tid == 0 && node0 + NPB >= n)          // last bucket: close the CSR
        rowstart[n] = ebase + cnt_b;
    __syncthreads();
    for (int i = tid; i < cnt_b; i += 512) {
        unsigned p = mp[i];
        int pos = atomicAdd(&lcur[p & (NPB - 1)], 1);
        eidx[ebase + pos] = (int)(p >> BKT_SHIFT);  // contiguous ~65 KB window
    }
    // ---- cvec side-job (block 0 only; ready before gemm1 launches) ----
    if (b == 0 && tid < 64) {
        float inv_n = 1.0f / (float)n;
        float acc = 0.f;
        for (int k = 0; k < 64; ++k) acc += (sums[k] * inv_n) * W1[(64 + k) * 64 + tid];
        cvec[tid] = acc;
    }
}

// ---------- h1s(bf16) = dis[row] * (x @ W1[:64] + c); measured-good inner loop ----------
__global__ __launch_bounds__(256, 4) void gemm1_kernel(
        const float* __restrict__ x, const float* __restrict__ W1,
        const float* __restrict__ c, const float* __restrict__ dis,
        unsigned short* __restrict__ h1s, int n) {
    __shared__ float Ws[64 * 64];   // [k][j]
    __shared__ float Xs[64 * 68];   // pad 68
    int tid = threadIdx.x;
    int row0 = blockIdx.x * 64;
    {
        const float4* w4 = (const float4*)W1;
        float4* s4 = (float4*)Ws;
        for (int i = tid; i < 1024; i += 256) s4[i] = w4[i];
    }
    for (int i = tid; i < 1024; i += 256) {
        int r = i >> 4, c4 = (i & 15) * 4;
        int gr = row0 + r;
        float4 xv = make_float4(0.f, 0.f, 0.f, 0.f);
        if (gr < n) xv = *(const float4*)&x[(size_t)gr * 64 + c4];
        *(float4*)&Xs[r * 68 + c4] = xv;
    }
    __syncthreads();
    int c16 = tid & 15;
    int rb = (tid >> 4) * 4;
    float4 cj = ((const float4*)c)[c16];
    float4 a0 = cj, a1 = cj, a2 = cj, a3 = cj;
#pragma unroll 4
    for (int k = 0; k < 64; ++k) {
        float4 w = *(const float4*)&Ws[k * 64 + c16 * 4];
        float x0 = Xs[(rb + 0) * 68 + k];
        float x1 = Xs[(rb + 1) * 68 + k];
        float x2 = Xs[(rb + 2) * 68 + k];
        float x3 = Xs[(rb + 3) * 68 + k];
        a0.x += x0 * w.x; a0.y += x0 * w.y; a0.z += x0 * w.z; a0.w += x0 * w.w;
        a1.x += x1 * w.x; a1.y += x1 * w.y; a1.z += x1 * w.z; a1.w += x1 * w.w;
        a2.x += x2 * w.x; a2.y += x2 * w.y; a2.z += x2 * w.z; a2.w += x2 * w.w;
        a3.x += x3 * w.x; a3.y += x3 * w.y; a3.z += x3 * w.z; a3.w += x3 * w.w;
    }
    float4 accs[4] = {a0, a1, a2, a3};
#pragma unroll
    for (int r = 0; r < 4; ++r) {
        int gr = row0 + rb + r;
        if (gr < n) {
            float dv = dis[gr];
            float4 o = accs[r];
            ushort4 hs;
            hs.x = f2bf(o.x * dv);
            hs.y = f2bf(o.y * dv);
            hs.z = f2bf(o.z * dv);
            hs.w = f2bf(o.w * dv);
            *(ushort4*)&h1s[(size_t)gr * 64 + c16 * 4] = hs;
        }
    }
}

// ---------- layer-1 gather: 16 lanes/edge, 16 edges/iter (4 loads in flight) ----------
__global__ void gather1_kernel(const int* __restrict__ rowstart,
                               const int* __restrict__ eidx, const float* __restrict__ dis,
                               const unsigned short* __restrict__ h1s,
                               const float* __restrict__ b1, const float* __restrict__ W2,
                               float* __restrict__ h2s, int n) {
    int lane = threadIdx.x & 63;
    int node = blockIdx.x * 4 + (threadIdx.x >> 6);
    if (node >= n) return;
    int rs = rowstart[node];
    int re = rowstart[node + 1];
    int dn = re - rs;
    int m = dn < 64 ? dn : 64;
    int eHeld = (lane < m) ? eidx[rs + lane] : 0;  // one coalesced load for <=64 edges
    int g  = lane >> 4;        // edge subgroup 0..3
    int fb = (lane & 15) * 4;  // feature base
    float4 acc = make_float4(0.f, 0.f, 0.f, 0.f);
    int j = 0;
    for (; j + 16 <= m; j += 16) {         // 16 edges per iter, 4 loads in flight
        int s0 = __shfl(eHeld, j + g, 64);
        int s1 = __shfl(eHeld, j + 4 + g, 64);
        int s2 = __shfl(eHeld, j + 8 + g, 64);
        int s3 = __shfl(eHeld, j + 12 + g, 64);
        ushort4 h0 = *(const ushort4*)&h1s[((size_t)s0 << 6) + fb];
        ushort4 h1 = *(const ushort4*)&h1s[((size_t)s1 << 6) + fb];
        ushort4 h2 = *(const ushort4*)&h1s[((size_t)s2 << 6) + fb];
        ushort4 h3 = *(const ushort4*)&h1s[((size_t)s3 << 6) + fb];
        acc.x += (bf2f(h0.x) + bf2f(h1.x)) + (bf2f(h2.x) + bf2f(h3.x));
        acc.y += (bf2f(h0.y) + bf2f(h1.y)) + (bf2f(h2.y) + bf2f(h3.y));
        acc.z += (bf2f(h0.z) + bf2f(h1.z)) + (bf2f(h2.z) + bf2f(h3.z));
        acc.w += (bf2f(h0.w) + bf2f(h1.w)) + (bf2f(h2.w) + bf2f(h3.w));
    }
    for (; j + 8 <= m; j += 8) {           // 8-edge tail, 2 loads
        int s0 = __shfl(eHeld, j + g, 64);
        int s1 = __shfl(eHeld, j + 4 + g, 64);
        ushort4 h0 = *(const ushort4*)&h1s[((size_t)s0 << 6) + fb];
        ushort4 h1 = *(const ushort4*)&h1s[((size_t)s1 << 6) + fb];
        acc.x += bf2f(h0.x) + bf2f(h1.x);
        acc.y += bf2f(h0.y) + bf2f(h1.y);
        acc.z += bf2f(h0.z) + bf2f(h1.z);
        acc.w += bf2f(h0.w) + bf2f(h1.w);
    }
    for (; j < m; j += 4) {                // ragged tail, 0..1 iters
        int jj = j + g;
        int s = __shfl(eHeld, jj < m ? jj : 0, 64);
        if (jj < m) {
            ushort4 h = *(const ushort4*)&h1s[((size_t)s << 6) + fb];
            acc.x += bf2f(h.x);
            acc.y += bf2f(h.y);
            acc.z += bf2f(h.z);
            acc.w += bf2f(h.w);
        }
    }
    for (int t = 64; t < dn; ++t) {        // deg > 64: astronomically rare here
        if (g == 0) {
            int s = eidx[rs + t];
            ushort4 h = *(const ushort4*)&h1s[((size_t)s << 6) + fb];
            acc.x += bf2f(h.x);
            acc.y += bf2f(h.y);
            acc.z += bf2f(h.z);
            acc.w += bf2f(h.w);
        }
    }
    // reduce across the 4 edge subgroups
    acc.x += __shfl_xor(acc.x, 16, 64); acc.x += __shfl_xor(acc.x, 32, 64);
    acc.y += __shfl_xor(acc.y, 16, 64); acc.y += __shfl_xor(acc.y, 32, 64);
    acc.z += __shfl_xor(acc.z, 16, 64); acc.z += __shfl_xor(acc.z, 32, 64);
    acc.w += __shfl_xor(acc.w, 16, 64); acc.w += __shfl_xor(acc.w, 32, 64);
    float di = dis[node];
    float4 bv = ((const float4*)b1)[lane & 15];
    float4 w0 = ((const float4*)W2)[(lane & 15) * 2];
    float4 w1 = ((const float4*)W2)[(lane & 15) * 2 + 1];
    float t0 = fmaxf(di * acc.x + bv.x, 0.f);
    float t1 = fmaxf(di * acc.y + bv.y, 0.f);
    float t2 = fmaxf(di * acc.z + bv.z, 0.f);
    float t3 = fmaxf(di * acc.w + bv.w, 0.f);
    float v0 = t0 * w0.x + t1 * w0.z + t2 * w1.x + t3 * w1.z;
    float v1 = t0 * w0.y + t1 * w0.w + t2 * w1.y + t3 * w1.w;
#pragma unroll
    for (int off = 1; off <= 8; off <<= 1) {   // sum the 16 feature classes
        v0 += __shfl_xor(v0, off, 64);
        v1 += __shfl_xor(v1, off, 64);
    }
    if (lane == 0) {
        h2s[(size_t)node * 2 + 0] = di * v0;
        h2s[(size_t)node * 2 + 1] = di * v1;
    }
}

// ---------- layer-2 gather, one thread per node ----------
__global__ void gather2_kernel(const int* __restrict__ rowstart,
                               const int* __restrict__ eidx, const float* __restrict__ dis,
                               const float* __restrict__ h2s, const float* __restrict__ b2,
                               float* __restrict__ out, int n) {
    int i = blockIdx.x * blockDim.x + threadIdx.x;
    if (i >= n) return;
    int rs = rowstart[i];
    int dn = rowstart[i + 1] - rs;
    float a0 = 0.f, a1 = 0.f, b0 = 0.f, b1v = 0.f;
    int j = 0;
    for (; j + 2 <= dn; j += 2) {
        int s0 = eidx[rs + j];
        int s1 = eidx[rs + j + 1];
        a0 += h2s[(size_t)s0 * 2 + 0];
        a1 += h2s[(size_t)s0 * 2 + 1];
        b0 += h2s[(size_t)s1 * 2 + 0];
        b1v += h2s[(size_t)s1 * 2 + 1];
    }
    if (j < dn) {
        int s0 = eidx[rs + j];
        a0 += h2s[(size_t)s0 * 2 + 0];
        a1 += h2s[(size_t)s0 * 2 + 1];
    }
    float di = dis[i];
    out[(size_t)i * 2 + 0] = di * (a0 + b0) + b2[0];
    out[(size_t)i * 2 + 1] = di * (a1 + b1v) + b2[1];
}

extern "C" void kernel_launch(void* const* d_in, const int* in_sizes, int n_in,
                              void* d_out, int out_size, void* d_ws, size_t ws_size,
                              hipStream_t stream) {
    const float* x  = (const float*)d_in[0];
    const int*   ei = (const int*)d_in[1];
    const float* W1 = (const float*)d_in[2];
    const float* b1 = (const float*)d_in[3];
    const float* W2 = (const float*)d_in[4];
    const float* b2 = (const float*)d_in[5];
    float* out = (float*)d_out;

    const int n = in_sizes[0] / 64;   // 100000
    const int e = in_sizes[1] / 2;    // 1600000
    const int* srcI = ei;
    const int* dstI = ei + e;

    // workspace layout (256-B aligned segments); sums+cursor adjacent -> 1 memset
    char* p = (char*)d_ws;
    int* rowstart = (int*)p;    p += ((size_t)(n + 1) * 4 + 255) & ~255ull;
    float* dis    = (float*)p;  p += ((size_t)n * 4 + 255) & ~255ull;
    float* sums   = (float*)p;                  // 256 B
    int* cursor   = (int*)(p + 256);            // BKT * 128 B padded slots
    char* zbase   = p;          p += 256 + BKT * CUR_STRIDE * 4;  // 16,640 B
    float* cvec   = (float*)p;  p += 256;
    int* eidx     = (int*)p;    p += ((size_t)e * 4 + 255) & ~255ull;
    // union: pairs (9.4 MB packed) dead before gemm1 writes h1s (bf16, 12.8 MB)
    unsigned* pairs      = (unsigned*)p;
    unsigned short* h1s  = (unsigned short*)p;
    {
        size_t pairs_sz = (size_t)BKT * BKT_CAP * 4;
        size_t h1s_sz   = (size_t)n * 64 * 2;
        size_t u = pairs_sz > h1s_sz ? pairs_sz : h1s_sz;
        p += (u + 255) & ~255ull;
    }
    float* h2s    = (float*)p;

    hipMemsetAsync(zbase, 0, 256 + BKT * CUR_STRIDE * 4, stream);

    const int nchunks = (e + CHUNK - 1) / CHUNK;           // 391
    const int nbkt    = (n + NPB - 1) / NPB;               // 98

    bucketAC_kernel<<<CS_BLK + nchunks, 512, 0, stream>>>(srcI, dstI, e, pairs, cursor,
                                                          x, sums, n);
    csrB_kernel<<<nbkt, 512, 0, stream>>>(pairs, cursor, dis, rowstart, eidx, n,
                                          sums, W1, cvec);
    gemm1_kernel<<<(n + 63) / 64, 256, 0, stream>>>(x, W1, cvec, dis, h1s, n);
    gather1_kernel<<<(n + 3) / 4, 256, 0, stream>>>(rowstart, eidx, dis, h1s, b1, W2, h2s, n);
    gather2_kernel<<<(n + 255) / 256, 256, 0, stream>>>(rowstart, eidx, dis, h2s, b2, out, n);
}

// Round 11
// 187.053 us; speedup vs baseline: 4.6586x; 1.0731x over previous
//
#include <hip/hip_runtime.h>

// GCN 2-layer, CSR-by-dst gather formulation; h1s in bf16.
// R10: NPB 256 (391 buckets -> csrB fills the machine; bucketA atomics spread
//      over 391 LDS counters). gemm1 via mfma_f32_16x16x32_bf16 with operand
//      swap (A=W^T frag, B=x frag) -> C lands as 4 consecutive cols/lane.
// out = A_hat( relu( A_hat( [x|mean]@W1 ) + b1 ) @ W2 ) + b2
// Identity: [x|mean]@W1 = x@W1[:64] + c, c = mean@W1[64:].
// Pre-scaling: h1s[s] = dis[s]*(xW1+c)[s];  h2s[s] = dis[s]*(relu(.)@W2)[s].

#define NPB        256     // nodes per bucket
#define NPB_SHIFT  8
#define BKTS       512     // scan width (>= 391 buckets, pow2)
#define BKT_CAP    5120    // mean 4096 + 16 sigma
#define CHUNK      4096    // edges per bucketA block
#define EPT        8       // CHUNK / 512 threads
#define CS_BLK     64      // colsum blocks prepended to bucketA grid
#define CUR_STRIDE 32      // ints per cursor slot (128-B line each)

using bf16x8 = __attribute__((ext_vector_type(8))) short;  // 8 bf16 (4 VGPRs)
using f32x4  = __attribute__((ext_vector_type(4))) float;

__device__ __forceinline__ unsigned short f2bf(float v) {
    unsigned u = __float_as_uint(v);
    u += 0x7FFFu + ((u >> 16) & 1u);   // round-to-nearest-even
    return (unsigned short)(u >> 16);
}
__device__ __forceinline__ float bf2f(unsigned short h) {
    return __uint_as_float((unsigned)h << 16);
}

// ---------- pass A: colsum (0..63) + W^T->bf16 (64) + multi-split (rest) ----------
__global__ __launch_bounds__(512) void bucketAC_kernel(
        const int* __restrict__ src, const int* __restrict__ dst,
        int e, unsigned* __restrict__ pairs, int* __restrict__ cursor,
        const float* __restrict__ x, float* __restrict__ sums,
        const float* __restrict__ W1, unsigned short* __restrict__ wtg, int n) {
    int tid = threadIdx.x;
    if (blockIdx.x < CS_BLK) {
        // ---- colsum side-job: column sums of x via float4 grid-stride ----
        __shared__ float4 s4[512];
        int cb = blockIdx.x;
        const float4* x4 = (const float4*)x;
        int total4 = n * 16;
        float4 acc = make_float4(0.f, 0.f, 0.f, 0.f);
        for (int i = cb * 512 + tid; i < total4; i += CS_BLK * 512) {
            float4 v = x4[i];
            acc.x += v.x; acc.y += v.y; acc.z += v.z; acc.w += v.w;
        }
        s4[tid] = acc;
        __syncthreads();
        if (tid < 16) {
            float4 v = s4[tid];
            for (int k = 1; k < 32; ++k) {
                float4 w = s4[tid + 16 * k];
                v.x += w.x; v.y += w.y; v.z += w.z; v.w += w.w;
            }
            atomicAdd(&sums[tid * 4 + 0], v.x);
            atomicAdd(&sums[tid * 4 + 1], v.y);
            atomicAdd(&sums[tid * 4 + 2], v.z);
            atomicAdd(&sums[tid * 4 + 3], v.w);
        }
        return;
    }
    if (blockIdx.x == CS_BLK) {
        // ---- W transpose side-job: wtg[j*64+k] = bf16(W1[k*64+j]), k<64 ----
        for (int i = tid; i < 4096; i += 512) {
            int k = i >> 6, j = i & 63;
            wtg[j * 64 + k] = f2bf(W1[k * 64 + j]);
        }
        return;
    }
    // ---- bucket multi-split: packed 4-B records (src<<8 | dst&255) ----
    __shared__ int cnt[BKTS], sb[BKTS], gpos[BKTS];
    __shared__ unsigned stage[CHUNK];
    __shared__ unsigned short bb[CHUNK];
    int chunkStart = (blockIdx.x - CS_BLK - 1) * CHUNK;
    int v = e - chunkStart;
    if (v > CHUNK) v = CHUNK;
    cnt[tid] = 0;
    __syncthreads();
    int myb[EPT], myoff[EPT];
    unsigned myp[EPT];
#pragma unroll
    for (int t = 0; t < EPT; ++t) {
        int i = chunkStart + t * 512 + tid;
        myb[t] = -1;
        if (i < e) {
            int s = src[i], d = dst[i];
            myb[t] = d >> NPB_SHIFT;
            myp[t] = ((unsigned)s << NPB_SHIFT) | (unsigned)(d & (NPB - 1));
            myoff[t] = atomicAdd(&cnt[myb[t]], 1);
        }
    }
    __syncthreads();
    sb[tid] = cnt[tid];
    __syncthreads();
    for (int off = 1; off < BKTS; off <<= 1) {
        int t = (tid >= off) ? sb[tid - off] : 0;
        __syncthreads();
        sb[tid] += t;
        __syncthreads();
    }
    {
        int excl = tid ? sb[tid - 1] : 0;
        int cb = cnt[tid];
        if (cb > 0) {
            int gb = atomicAdd(&cursor[tid * CUR_STRIDE], cb);  // private line
            gpos[tid] = tid * BKT_CAP + gb - excl;
        }
        cnt[tid] = excl;  // reuse as stage base
    }
    __syncthreads();
#pragma unroll
    for (int t = 0; t < EPT; ++t) {
        if (myb[t] >= 0) {
            int p = cnt[myb[t]] + myoff[t];
            stage[p] = myp[t];
            bb[p] = (unsigned short)myb[t];
        }
    }
    __syncthreads();
    for (int j = tid; j < v; j += 512) {
        int bk = bb[j];
        int wi = gpos[bk] + j;
        if (wi < (bk + 1) * BKT_CAP) pairs[wi] = stage[j];  // contiguous runs
    }
}

// ---------- pass B: per-bucket hist+scan+fill; emits dis+rowstart; block0: cvec ----------
__global__ __launch_bounds__(512) void csrB_kernel(
        const unsigned* __restrict__ pairs, const int* __restrict__ cursor,
        float* __restrict__ dis, int* __restrict__ rowstart,
        int* __restrict__ eidx, int n,
        const float* __restrict__ sums, const float* __restrict__ W1,
        float* __restrict__ cvec) {
    __shared__ int ldeg[NPB];
    __shared__ int lcur[NPB];
    __shared__ int scanbuf[512];
    __shared__ int s_ebase;
    int b = blockIdx.x;
    int tid = threadIdx.x;
    int node0 = b << NPB_SHIFT;
    if (node0 >= n) return;
    int nl = n - node0;
    if (nl > NPB) nl = NPB;
    int cnt_b = cursor[b * CUR_STRIDE];
    if (cnt_b > BKT_CAP) cnt_b = BKT_CAP;
    if (tid < NPB) ldeg[tid] = 0;
    if (tid == 0) s_ebase = 0;
    __syncthreads();
    if (tid < b) atomicAdd(&s_ebase, cursor[tid * CUR_STRIDE]);  // parallel prefix
    const unsigned* mp = pairs + (size_t)b * BKT_CAP;
    for (int i = tid; i < cnt_b; i += 512)
        atomicAdd(&ldeg[mp[i] & (NPB - 1)], 1);
    __syncthreads();
    scanbuf[tid] = (tid < NPB) ? ldeg[tid] : 0;
    __syncthreads();
    for (int off = 1; off < 512; off <<= 1) {
        int t = (tid >= off) ? scanbuf[tid - off] : 0;
        __syncthreads();
        scanbuf[tid] += t;
        __syncthreads();
    }
    int ebase = s_ebase;
    if (tid < NPB) {
        int ex = tid ? scanbuf[tid - 1] : 0;
        lcur[tid] = ex;
        if (tid < nl) {
            int dv = ldeg[tid];
            rowstart[node0 + tid] = ebase + ex;
            dis[node0 + tid] = dv > 0 ? rsqrtf((float)dv) : 0.f;
        }
    }
    if (tid == 0 && node0 + NPB >= n)          // last bucket: close the CSR
        rowstart[n] = ebase + cnt_b;
    __syncthreads();
    for (int i = tid; i < cnt_b; i += 512) {
        unsigned p = mp[i];
        int pos = atomicAdd(&lcur[p & (NPB - 1)], 1);
        eidx[ebase + pos] = (int)(p >> NPB_SHIFT);  // contiguous ~16 KB window
    }
    // ---- cvec side-job (block 0 only; ready before gemm1 launches) ----
    if (b == 0 && tid < 64) {
        float inv_n = 1.0f / (float)n;
        float acc = 0.f;
        for (int k = 0; k < 64; ++k) acc += (sums[k] * inv_n) * W1[(64 + k) * 64 + tid];
        cvec[tid] = acc;
    }
}

// ---------- h1s(bf16) = dis[row]*(x@W1[:64]+c) via MFMA 16x16x32 bf16 ----------
// Operand swap: A-slot = W^T fragment (m == output col), B-slot = x fragment
// (n == output row)  =>  D[m][n]: lane holds 4 consecutive cols of one row.
__global__ __launch_bounds__(256) void gemm1_kernel(
        const float* __restrict__ x, const unsigned short* __restrict__ wtg,
        const float* __restrict__ c, const float* __restrict__ dis,
        unsigned short* __restrict__ h1s, int n) {
    __shared__ unsigned short Xs[64 * 72];   // stride 72 bf16 (144 B): 2-way banks
    __shared__ unsigned short Ws[64 * 72];   // Wt[col][k]
    int tid = threadIdx.x;
    int row0 = blockIdx.x * 64;
    // stage W^T (bf16, already transposed in global)
    for (int i = tid; i < 1024; i += 256) {          // 1024 ushort4 chunks
        int j = i >> 4, k4 = (i & 15) * 4;
        *(ushort4*)&Ws[j * 72 + k4] = *(const ushort4*)&wtg[j * 64 + k4];
    }
    // stage x -> bf16
    for (int i = tid; i < 1024; i += 256) {
        int r = i >> 4, k4 = (i & 15) * 4;
        int gr = row0 + r;
        float4 xv = make_float4(0.f, 0.f, 0.f, 0.f);
        if (gr < n) xv = *(const float4*)&x[(size_t)gr * 64 + k4];
        ushort4 hv;
        hv.x = f2bf(xv.x); hv.y = f2bf(xv.y); hv.z = f2bf(xv.z); hv.w = f2bf(xv.w);
        *(ushort4*)&Xs[r * 72 + k4] = hv;
    }
    __syncthreads();
    int lane = tid & 63;
    int wv = tid >> 6;          // wave 0..3 -> rows wv*16..+15
    int l15 = lane & 15;
    int quad = lane >> 4;
    f32x4 acc0 = {0.f, 0.f, 0.f, 0.f}, acc1 = acc0, acc2 = acc0, acc3 = acc0;
    int xrow = wv * 16 + l15;
#pragma unroll
    for (int ks = 0; ks < 2; ++ks) {
        bf16x8 bfrag = *(const bf16x8*)&Xs[xrow * 72 + ks * 32 + quad * 8];
        bf16x8 a0 = *(const bf16x8*)&Ws[(0 * 16 + l15) * 72 + ks * 32 + quad * 8];
        bf16x8 a1 = *(const bf16x8*)&Ws[(1 * 16 + l15) * 72 + ks * 32 + quad * 8];
        bf16x8 a2 = *(const bf16x8*)&Ws[(2 * 16 + l15) * 72 + ks * 32 + quad * 8];
        bf16x8 a3 = *(const bf16x8*)&Ws[(3 * 16 + l15) * 72 + ks * 32 + quad * 8];
        acc0 = __builtin_amdgcn_mfma_f32_16x16x32_bf16(a0, bfrag, acc0, 0, 0, 0);
        acc1 = __builtin_amdgcn_mfma_f32_16x16x32_bf16(a1, bfrag, acc1, 0, 0, 0);
        acc2 = __builtin_amdgcn_mfma_f32_16x16x32_bf16(a2, bfrag, acc2, 0, 0, 0);
        acc3 = __builtin_amdgcn_mfma_f32_16x16x32_bf16(a3, bfrag, acc3, 0, 0, 0);
    }
    int grow = row0 + xrow;
    if (grow < n) {
        float dv = dis[grow];
        const float4* c4 = (const float4*)c;
        f32x4 accs[4] = {acc0, acc1, acc2, acc3};
#pragma unroll
        for (int t = 0; t < 4; ++t) {
            float4 cj = c4[t * 4 + quad];
            ushort4 hs;
            hs.x = f2bf((accs[t][0] + cj.x) * dv);
            hs.y = f2bf((accs[t][1] + cj.y) * dv);
            hs.z = f2bf((accs[t][2] + cj.z) * dv);
            hs.w = f2bf((accs[t][3] + cj.w) * dv);
            *(ushort4*)&h1s[(size_t)grow * 64 + t * 16 + quad * 4] = hs;
        }
    }
}

// ---------- layer-1 gather: 16 lanes/edge, 16 edges/iter (4 loads in flight) ----------
__global__ void gather1_kernel(const int* __restrict__ rowstart,
                               const int* __restrict__ eidx, const float* __restrict__ dis,
                               const unsigned short* __restrict__ h1s,
                               const float* __restrict__ b1, const float* __restrict__ W2,
                               float* __restrict__ h2s, int n) {
    int lane = threadIdx.x & 63;
    int node = blockIdx.x * 4 + (threadIdx.x >> 6);
    if (node >= n) return;
    int rs = rowstart[node];
    int re = rowstart[node + 1];
    int dn = re - rs;
    int m = dn < 64 ? dn : 64;
    int eHeld = (lane < m) ? eidx[rs + lane] : 0;  // one coalesced load for <=64 edges
    int g  = lane >> 4;        // edge subgroup 0..3
    int fb = (lane & 15) * 4;  // feature base
    float4 acc = make_float4(0.f, 0.f, 0.f, 0.f);
    int j = 0;
    for (; j + 16 <= m; j += 16) {         // 16 edges per iter, 4 loads in flight
        int s0 = __shfl(eHeld, j + g, 64);
        int s1 = __shfl(eHeld, j + 4 + g, 64);
        int s2 = __shfl(eHeld, j + 8 + g, 64);
        int s3 = __shfl(eHeld, j + 12 + g, 64);
        ushort4 h0 = *(const ushort4*)&h1s[((size_t)s0 << 6) + fb];
        ushort4 h1 = *(const ushort4*)&h1s[((size_t)s1 << 6) + fb];
        ushort4 h2 = *(const ushort4*)&h1s[((size_t)s2 << 6) + fb];
        ushort4 h3 = *(const ushort4*)&h1s[((size_t)s3 << 6) + fb];
        acc.x += (bf2f(h0.x) + bf2f(h1.x)) + (bf2f(h2.x) + bf2f(h3.x));
        acc.y += (bf2f(h0.y) + bf2f(h1.y)) + (bf2f(h2.y) + bf2f(h3.y));
        acc.z += (bf2f(h0.z) + bf2f(h1.z)) + (bf2f(h2.z) + bf2f(h3.z));
        acc.w += (bf2f(h0.w) + bf2f(h1.w)) + (bf2f(h2.w) + bf2f(h3.w));
    }
    for (; j + 8 <= m; j += 8) {           // 8-edge tail, 2 loads
        int s0 = __shfl(eHeld, j + g, 64);
        int s1 = __shfl(eHeld, j + 4 + g, 64);
        ushort4 h0 = *(const ushort4*)&h1s[((size_t)s0 << 6) + fb];
        ushort4 h1 = *(const ushort4*)&h1s[((size_t)s1 << 6) + fb];
        acc.x += bf2f(h0.x) + bf2f(h1.x);
        acc.y += bf2f(h0.y) + bf2f(h1.y);
        acc.z += bf2f(h0.z) + bf2f(h1.z);
        acc.w += bf2f(h0.w) + bf2f(h1.w);
    }
    for (; j < m; j += 4) {                // ragged tail, 0..1 iters
        int jj = j + g;
        int s = __shfl(eHeld, jj < m ? jj : 0, 64);
        if (jj < m) {
            ushort4 h = *(const ushort4*)&h1s[((size_t)s << 6) + fb];
            acc.x += bf2f(h.x);
            acc.y += bf2f(h.y);
            acc.z += bf2f(h.z);
            acc.w += bf2f(h.w);
        }
    }
    for (int t = 64; t < dn; ++t) {        // deg > 64: astronomically rare here
        if (g == 0) {
            int s = eidx[rs + t];
            ushort4 h = *(const ushort4*)&h1s[((size_t)s << 6) + fb];
            acc.x += bf2f(h.x);
            acc.y += bf2f(h.y);
            acc.z += bf2f(h.z);
            acc.w += bf2f(h.w);
        }
    }
    // reduce across the 4 edge subgroups
    acc.x += __shfl_xor(acc.x, 16, 64); acc.x += __shfl_xor(acc.x, 32, 64);
    acc.y += __shfl_xor(acc.y, 16, 64); acc.y += __shfl_xor(acc.y, 32, 64);
    acc.z += __shfl_xor(acc.z, 16, 64); acc.z += __shfl_xor(acc.z, 32, 64);
    acc.w += __shfl_xor(acc.w, 16, 64); acc.w += __shfl_xor(acc.w, 32, 64);
    float di = dis[node];
    float4 bv = ((const float4*)b1)[lane & 15];
    float4 w0 = ((const float4*)W2)[(lane & 15) * 2];
    float4 w1 = ((const float4*)W2)[(lane & 15) * 2 + 1];
    float t0 = fmaxf(di * acc.x + bv.x, 0.f);
    float t1 = fmaxf(di * acc.y + bv.y, 0.f);
    float t2 = fmaxf(di * acc.z + bv.z, 0.f);
    float t3 = fmaxf(di * acc.w + bv.w, 0.f);
    float v0 = t0 * w0.x + t1 * w0.z + t2 * w1.x + t3 * w1.z;
    float v1 = t0 * w0.y + t1 * w0.w + t2 * w1.y + t3 * w1.w;
#pragma unroll
    for (int off = 1; off <= 8; off <<= 1) {   // sum the 16 feature classes
        v0 += __shfl_xor(v0, off, 64);
        v1 += __shfl_xor(v1, off, 64);
    }
    if (lane == 0) {
        h2s[(size_t)node * 2 + 0] = di * v0;
        h2s[(size_t)node * 2 + 1] = di * v1;
    }
}

// ---------- layer-2 gather, one thread per node ----------
__global__ void gather2_kernel(const int* __restrict__ rowstart,
                               const int* __restrict__ eidx, const float* __restrict__ dis,
                               const float* __restrict__ h2s, const float* __restrict__ b2,
                               float* __restrict__ out, int n) {
    int i = blockIdx.x * blockDim.x + threadIdx.x;
    if (i >= n) return;
    int rs = rowstart[i];
    int dn = rowstart[i + 1] - rs;
    float a0 = 0.f, a1 = 0.f, b0 = 0.f, b1v = 0.f;
    int j = 0;
    for (; j + 2 <= dn; j += 2) {
        int s0 = eidx[rs + j];
        int s1 = eidx[rs + j + 1];
        a0 += h2s[(size_t)s0 * 2 + 0];
        a1 += h2s[(size_t)s0 * 2 + 1];
        b0 += h2s[(size_t)s1 * 2 + 0];
        b1v += h2s[(size_t)s1 * 2 + 1];
    }
    if (j < dn) {
        int s0 = eidx[rs + j];
        a0 += h2s[(size_t)s0 * 2 + 0];
        a1 += h2s[(size_t)s0 * 2 + 1];
    }
    float di = dis[i];
    out[(size_t)i * 2 + 0] = di * (a0 + b0) + b2[0];
    out[(size_t)i * 2 + 1] = di * (a1 + b1v) + b2[1];
}

extern "C" void kernel_launch(void* const* d_in, const int* in_sizes, int n_in,
                              void* d_out, int out_size, void* d_ws, size_t ws_size,
                              hipStream_t stream) {
    const float* x  = (const float*)d_in[0];
    const int*   ei = (const int*)d_in[1];
    const float* W1 = (const float*)d_in[2];
    const float* b1 = (const float*)d_in[3];
    const float* W2 = (const float*)d_in[4];
    const float* b2 = (const float*)d_in[5];
    float* out = (float*)d_out;

    const int n = in_sizes[0] / 64;   // 100000
    const int e = in_sizes[1] / 2;    // 1600000
    const int* srcI = ei;
    const int* dstI = ei + e;
    const int nbkt = (n + NPB - 1) >> NPB_SHIFT;   // 391

    // workspace layout (256-B aligned segments); sums+cursor adjacent -> 1 memset
    char* p = (char*)d_ws;
    int* rowstart = (int*)p;    p += ((size_t)(n + 1) * 4 + 255) & ~255ull;
    float* dis    = (float*)p;  p += ((size_t)n * 4 + 255) & ~255ull;
    float* sums   = (float*)p;                  // 256 B
    int* cursor   = (int*)(p + 256);            // nbkt * 128-B padded slots
    size_t zsize  = 256 + (size_t)nbkt * CUR_STRIDE * 4;
    char* zbase   = p;          p += (zsize + 255) & ~255ull;
    float* cvec   = (float*)p;  p += 256;
    unsigned short* wtg = (unsigned short*)p;  p += (4096 * 2 + 255) & ~255ull;
    int* eidx     = (int*)p;    p += ((size_t)e * 4 + 255) & ~255ull;
    // union: pairs (8.0 MB packed) dead before gemm1 writes h1s (bf16, 12.8 MB)
    unsigned* pairs      = (unsigned*)p;
    unsigned short* h1s  = (unsigned short*)p;
    {
        size_t pairs_sz = (size_t)nbkt * BKT_CAP * 4;
        size_t h1s_sz   = (size_t)n * 64 * 2;
        size_t u = pairs_sz > h1s_sz ? pairs_sz : h1s_sz;
        p += (u + 255) & ~255ull;
    }
    float* h2s    = (float*)p;

    hipMemsetAsync(zbase, 0, zsize, stream);

    const int nchunks = (e + CHUNK - 1) / CHUNK;           // 391

    bucketAC_kernel<<<CS_BLK + 1 + nchunks, 512, 0, stream>>>(srcI, dstI, e, pairs, cursor,
                                                              x, sums, W1, wtg, n);
    csrB_kernel<<<nbkt, 512, 0, stream>>>(pairs, cursor, dis, rowstart, eidx, n,
                                          sums, W1, cvec);
    gemm1_kernel<<<(n + 63) / 64, 256, 0, stream>>>(x, wtg, cvec, dis, h1s, n);
    gather1_kernel<<<(n + 3) / 4, 256, 0, stream>>>(rowstart, eidx, dis, h1s, b1, W2, h2s, n);
    gather2_kernel<<<(n + 255) / 256, 256, 0, stream>>>(rowstart, eidx, dis, h2s, b2, out, n);
}

// Round 12
// 186.676 us; speedup vs baseline: 4.6680x; 1.0020x over previous
//
#include <hip/hip_runtime.h>

// GCN 2-layer, CSR-by-dst gather formulation; h1s in bf16.
// R11: gather1 -> 32 lanes/edge (ushort2/lane): 8 loads in flight per wave
//      (2x MLP on the L2-miss path). gather2 -> wave/4-nodes, lane-per-edge.
// out = A_hat( relu( A_hat( [x|mean]@W1 ) + b1 ) @ W2 ) + b2
// Identity: [x|mean]@W1 = x@W1[:64] + c, c = mean@W1[64:].
// Pre-scaling: h1s[s] = dis[s]*(xW1+c)[s];  h2s[s] = dis[s]*(relu(.)@W2)[s].

#define NPB        256     // nodes per bucket
#define NPB_SHIFT  8
#define BKTS       512     // scan width (>= 391 buckets, pow2)
#define BKT_CAP    5120    // mean 4096 + 16 sigma
#define CHUNK      4096    // edges per bucketA block
#define EPT        8       // CHUNK / 512 threads
#define CS_BLK     64      // colsum blocks prepended to bucketA grid
#define CUR_STRIDE 32      // ints per cursor slot (128-B line each)

using bf16x8 = __attribute__((ext_vector_type(8))) short;  // 8 bf16 (4 VGPRs)
using f32x4  = __attribute__((ext_vector_type(4))) float;

__device__ __forceinline__ unsigned short f2bf(float v) {
    unsigned u = __float_as_uint(v);
    u += 0x7FFFu + ((u >> 16) & 1u);   // round-to-nearest-even
    return (unsigned short)(u >> 16);
}
__device__ __forceinline__ float bf2f(unsigned short h) {
    return __uint_as_float((unsigned)h << 16);
}
// two bf16 packed in a uint -> two floats (2 VALU)
__device__ __forceinline__ float bfu_lo(unsigned u) { return __uint_as_float(u << 16); }
__device__ __forceinline__ float bfu_hi(unsigned u) { return __uint_as_float(u & 0xFFFF0000u); }

// ---------- pass A: colsum (0..63) + W^T->bf16 (64) + multi-split (rest) ----------
__global__ __launch_bounds__(512) void bucketAC_kernel(
        const int* __restrict__ src, const int* __restrict__ dst,
        int e, unsigned* __restrict__ pairs, int* __restrict__ cursor,
        const float* __restrict__ x, float* __restrict__ sums,
        const float* __restrict__ W1, unsigned short* __restrict__ wtg, int n) {
    int tid = threadIdx.x;
    if (blockIdx.x < CS_BLK) {
        // ---- colsum side-job: column sums of x via float4 grid-stride ----
        __shared__ float4 s4[512];
        int cb = blockIdx.x;
        const float4* x4 = (const float4*)x;
        int total4 = n * 16;
        float4 acc = make_float4(0.f, 0.f, 0.f, 0.f);
        for (int i = cb * 512 + tid; i < total4; i += CS_BLK * 512) {
            float4 v = x4[i];
            acc.x += v.x; acc.y += v.y; acc.z += v.z; acc.w += v.w;
        }
        s4[tid] = acc;
        __syncthreads();
        if (tid < 16) {
            float4 v = s4[tid];
            for (int k = 1; k < 32; ++k) {
                float4 w = s4[tid + 16 * k];
                v.x += w.x; v.y += w.y; v.z += w.z; v.w += w.w;
            }
            atomicAdd(&sums[tid * 4 + 0], v.x);
            atomicAdd(&sums[tid * 4 + 1], v.y);
            atomicAdd(&sums[tid * 4 + 2], v.z);
            atomicAdd(&sums[tid * 4 + 3], v.w);
        }
        return;
    }
    if (blockIdx.x == CS_BLK) {
        // ---- W transpose side-job: wtg[j*64+k] = bf16(W1[k*64+j]), k<64 ----
        for (int i = tid; i < 4096; i += 512) {
            int k = i >> 6, j = i & 63;
            wtg[j * 64 + k] = f2bf(W1[k * 64 + j]);
        }
        return;
    }
    // ---- bucket multi-split: packed 4-B records (src<<8 | dst&255) ----
    __shared__ int cnt[BKTS], sb[BKTS], gpos[BKTS];
    __shared__ unsigned stage[CHUNK];
    __shared__ unsigned short bb[CHUNK];
    int chunkStart = (blockIdx.x - CS_BLK - 1) * CHUNK;
    int v = e - chunkStart;
    if (v > CHUNK) v = CHUNK;
    cnt[tid] = 0;
    __syncthreads();
    int myb[EPT], myoff[EPT];
    unsigned myp[EPT];
#pragma unroll
    for (int t = 0; t < EPT; ++t) {
        int i = chunkStart + t * 512 + tid;
        myb[t] = -1;
        if (i < e) {
            int s = src[i], d = dst[i];
            myb[t] = d >> NPB_SHIFT;
            myp[t] = ((unsigned)s << NPB_SHIFT) | (unsigned)(d & (NPB - 1));
            myoff[t] = atomicAdd(&cnt[myb[t]], 1);
        }
    }
    __syncthreads();
    sb[tid] = cnt[tid];
    __syncthreads();
    for (int off = 1; off < BKTS; off <<= 1) {
        int t = (tid >= off) ? sb[tid - off] : 0;
        __syncthreads();
        sb[tid] += t;
        __syncthreads();
    }
    {
        int excl = tid ? sb[tid - 1] : 0;
        int cb = cnt[tid];
        if (cb > 0) {
            int gb = atomicAdd(&cursor[tid * CUR_STRIDE], cb);  // private line
            gpos[tid] = tid * BKT_CAP + gb - excl;
        }
        cnt[tid] = excl;  // reuse as stage base
    }
    __syncthreads();
#pragma unroll
    for (int t = 0; t < EPT; ++t) {
        if (myb[t] >= 0) {
            int p = cnt[myb[t]] + myoff[t];
            stage[p] = myp[t];
            bb[p] = (unsigned short)myb[t];
        }
    }
    __syncthreads();
    for (int j = tid; j < v; j += 512) {
        int bk = bb[j];
        int wi = gpos[bk] + j;
        if (wi < (bk + 1) * BKT_CAP) pairs[wi] = stage[j];  // contiguous runs
    }
}

// ---------- pass B: per-bucket hist+scan+fill; emits dis+rowstart; block0: cvec ----------
__global__ __launch_bounds__(512) void csrB_kernel(
        const unsigned* __restrict__ pairs, const int* __restrict__ cursor,
        float* __restrict__ dis, int* __restrict__ rowstart,
        int* __restrict__ eidx, int n,
        const float* __restrict__ sums, const float* __restrict__ W1,
        float* __restrict__ cvec) {
    __shared__ int ldeg[NPB];
    __shared__ int lcur[NPB];
    __shared__ int scanbuf[512];
    __shared__ int s_ebase;
    int b = blockIdx.x;
    int tid = threadIdx.x;
    int node0 = b << NPB_SHIFT;
    if (node0 >= n) return;
    int nl = n - node0;
    if (nl > NPB) nl = NPB;
    int cnt_b = cursor[b * CUR_STRIDE];
    if (cnt_b > BKT_CAP) cnt_b = BKT_CAP;
    if (tid < NPB) ldeg[tid] = 0;
    if (tid == 0) s_ebase = 0;
    __syncthreads();
    if (tid < b) atomicAdd(&s_ebase, cursor[tid * CUR_STRIDE]);  // parallel prefix
    const unsigned* mp = pairs + (size_t)b * BKT_CAP;
    for (int i = tid; i < cnt_b; i += 512)
        atomicAdd(&ldeg[mp[i] & (NPB - 1)], 1);
    __syncthreads();
    scanbuf[tid] = (tid < NPB) ? ldeg[tid] : 0;
    __syncthreads();
    for (int off = 1; off < 512; off <<= 1) {
        int t = (tid >= off) ? scanbuf[tid - off] : 0;
        __syncthreads();
        scanbuf[tid] += t;
        __syncthreads();
    }
    int ebase = s_ebase;
    if (tid < NPB) {
        int ex = tid ? scanbuf[tid - 1] : 0;
        lcur[tid] = ex;
        if (tid < nl) {
            int dv = ldeg[tid];
            rowstart[node0 + tid] = ebase + ex;
            dis[node0 + tid] = dv > 0 ? rsqrtf((float)dv) : 0.f;
        }
    }
    if (tid == 0 && node0 + NPB >= n)          // last bucket: close the CSR
        rowstart[n] = ebase + cnt_b;
    __syncthreads();
    for (int i = tid; i < cnt_b; i += 512) {
        unsigned p = mp[i];
        int pos = atomicAdd(&lcur[p & (NPB - 1)], 1);
        eidx[ebase + pos] = (int)(p >> NPB_SHIFT);  // contiguous ~16 KB window
    }
    // ---- cvec side-job (block 0 only; ready before gemm1 launches) ----
    if (b == 0 && tid < 64) {
        float inv_n = 1.0f / (float)n;
        float acc = 0.f;
        for (int k = 0; k < 64; ++k) acc += (sums[k] * inv_n) * W1[(64 + k) * 64 + tid];
        cvec[tid] = acc;
    }
}

// ---------- h1s(bf16) = dis[row]*(x@W1[:64]+c) via MFMA 16x16x32 bf16 ----------
__global__ __launch_bounds__(256) void gemm1_kernel(
        const float* __restrict__ x, const unsigned short* __restrict__ wtg,
        const float* __restrict__ c, const float* __restrict__ dis,
        unsigned short* __restrict__ h1s, int n) {
    __shared__ unsigned short Xs[64 * 72];   // stride 72 bf16 (144 B): 2-way banks
    __shared__ unsigned short Ws[64 * 72];   // Wt[col][k]
    int tid = threadIdx.x;
    int row0 = blockIdx.x * 64;
    for (int i = tid; i < 1024; i += 256) {          // stage W^T (bf16)
        int j = i >> 4, k4 = (i & 15) * 4;
        *(ushort4*)&Ws[j * 72 + k4] = *(const ushort4*)&wtg[j * 64 + k4];
    }
    for (int i = tid; i < 1024; i += 256) {          // stage x -> bf16
        int r = i >> 4, k4 = (i & 15) * 4;
        int gr = row0 + r;
        float4 xv = make_float4(0.f, 0.f, 0.f, 0.f);
        if (gr < n) xv = *(const float4*)&x[(size_t)gr * 64 + k4];
        ushort4 hv;
        hv.x = f2bf(xv.x); hv.y = f2bf(xv.y); hv.z = f2bf(xv.z); hv.w = f2bf(xv.w);
        *(ushort4*)&Xs[r * 72 + k4] = hv;
    }
    __syncthreads();
    int lane = tid & 63;
    int wv = tid >> 6;
    int l15 = lane & 15;
    int quad = lane >> 4;
    f32x4 acc0 = {0.f, 0.f, 0.f, 0.f}, acc1 = acc0, acc2 = acc0, acc3 = acc0;
    int xrow = wv * 16 + l15;
#pragma unroll
    for (int ks = 0; ks < 2; ++ks) {
        bf16x8 bfrag = *(const bf16x8*)&Xs[xrow * 72 + ks * 32 + quad * 8];
        bf16x8 a0 = *(const bf16x8*)&Ws[(0 * 16 + l15) * 72 + ks * 32 + quad * 8];
        bf16x8 a1 = *(const bf16x8*)&Ws[(1 * 16 + l15) * 72 + ks * 32 + quad * 8];
        bf16x8 a2 = *(const bf16x8*)&Ws[(2 * 16 + l15) * 72 + ks * 32 + quad * 8];
        bf16x8 a3 = *(const bf16x8*)&Ws[(3 * 16 + l15) * 72 + ks * 32 + quad * 8];
        acc0 = __builtin_amdgcn_mfma_f32_16x16x32_bf16(a0, bfrag, acc0, 0, 0, 0);
        acc1 = __builtin_amdgcn_mfma_f32_16x16x32_bf16(a1, bfrag, acc1, 0, 0, 0);
        acc2 = __builtin_amdgcn_mfma_f32_16x16x32_bf16(a2, bfrag, acc2, 0, 0, 0);
        acc3 = __builtin_amdgcn_mfma_f32_16x16x32_bf16(a3, bfrag, acc3, 0, 0, 0);
    }
    int grow = row0 + xrow;
    if (grow < n) {
        float dv = dis[grow];
        const float4* c4 = (const float4*)c;
        f32x4 accs[4] = {acc0, acc1, acc2, acc3};
#pragma unroll
        for (int t = 0; t < 4; ++t) {
            float4 cj = c4[t * 4 + quad];
            ushort4 hs;
            hs.x = f2bf((accs[t][0] + cj.x) * dv);
            hs.y = f2bf((accs[t][1] + cj.y) * dv);
            hs.z = f2bf((accs[t][2] + cj.z) * dv);
            hs.w = f2bf((accs[t][3] + cj.w) * dv);
            *(ushort4*)&h1s[(size_t)grow * 64 + t * 16 + quad * 4] = hs;
        }
    }
}

// ---------- layer-1 gather: 32 lanes/edge (ushort2/lane), 8 loads in flight ----------
__global__ void gather1_kernel(const int* __restrict__ rowstart,
                               const int* __restrict__ eidx, const float* __restrict__ dis,
                               const unsigned short* __restrict__ h1s,
                               const float* __restrict__ b1, const float* __restrict__ W2,
                               float* __restrict__ h2s, int n) {
    int lane = threadIdx.x & 63;
    int node = blockIdx.x * 4 + (threadIdx.x >> 6);
    if (node >= n) return;
    int rs = rowstart[node];
    int re = rowstart[node + 1];
    int dn = re - rs;
    int m = dn < 64 ? dn : 64;
    int eHeld = (lane < m) ? eidx[rs + lane] : 0;  // one coalesced load for <=64 edges
    int sub = lane >> 5;        // edge subgroup 0..1
    int fp  = (lane & 31) * 2;  // feature pair base
    float ax = 0.f, ay = 0.f;
    int j = 0;
    for (; j + 16 <= m; j += 16) {        // 16 edges per iter, 8 loads in flight
        int s0 = __shfl(eHeld, j + 0 + sub, 64);
        int s1 = __shfl(eHeld, j + 2 + sub, 64);
        int s2 = __shfl(eHeld, j + 4 + sub, 64);
        int s3 = __shfl(eHeld, j + 6 + sub, 64);
        int s4 = __shfl(eHeld, j + 8 + sub, 64);
        int s5 = __shfl(eHeld, j + 10 + sub, 64);
        int s6 = __shfl(eHeld, j + 12 + sub, 64);
        int s7 = __shfl(eHeld, j + 14 + sub, 64);
        unsigned u0 = *(const unsigned*)&h1s[((size_t)s0 << 6) + fp];
        unsigned u1 = *(const unsigned*)&h1s[((size_t)s1 << 6) + fp];
        unsigned u2 = *(const unsigned*)&h1s[((size_t)s2 << 6) + fp];
        unsigned u3 = *(const unsigned*)&h1s[((size_t)s3 << 6) + fp];
        unsigned u4 = *(const unsigned*)&h1s[((size_t)s4 << 6) + fp];
        unsigned u5 = *(const unsigned*)&h1s[((size_t)s5 << 6) + fp];
        unsigned u6 = *(const unsigned*)&h1s[((size_t)s6 << 6) + fp];
        unsigned u7 = *(const unsigned*)&h1s[((size_t)s7 << 6) + fp];
        ax += (bfu_lo(u0) + bfu_lo(u1)) + (bfu_lo(u2) + bfu_lo(u3))
            + (bfu_lo(u4) + bfu_lo(u5)) + (bfu_lo(u6) + bfu_lo(u7));
        ay += (bfu_hi(u0) + bfu_hi(u1)) + (bfu_hi(u2) + bfu_hi(u3))
            + (bfu_hi(u4) + bfu_hi(u5)) + (bfu_hi(u6) + bfu_hi(u7));
    }
    for (; j + 8 <= m; j += 8) {          // 8-edge tail, 4 loads
        int s0 = __shfl(eHeld, j + 0 + sub, 64);
        int s1 = __shfl(eHeld, j + 2 + sub, 64);
        int s2 = __shfl(eHeld, j + 4 + sub, 64);
        int s3 = __shfl(eHeld, j + 6 + sub, 64);
        unsigned u0 = *(const unsigned*)&h1s[((size_t)s0 << 6) + fp];
        unsigned u1 = *(const unsigned*)&h1s[((size_t)s1 << 6) + fp];
        unsigned u2 = *(const unsigned*)&h1s[((size_t)s2 << 6) + fp];
        unsigned u3 = *(const unsigned*)&h1s[((size_t)s3 << 6) + fp];
        ax += (bfu_lo(u0) + bfu_lo(u1)) + (bfu_lo(u2) + bfu_lo(u3));
        ay += (bfu_hi(u0) + bfu_hi(u1)) + (bfu_hi(u2) + bfu_hi(u3));
    }
    for (; j + 4 <= m; j += 4) {          // 4-edge tail, 2 loads
        int s0 = __shfl(eHeld, j + 0 + sub, 64);
        int s1 = __shfl(eHeld, j + 2 + sub, 64);
        unsigned u0 = *(const unsigned*)&h1s[((size_t)s0 << 6) + fp];
        unsigned u1 = *(const unsigned*)&h1s[((size_t)s1 << 6) + fp];
        ax += bfu_lo(u0) + bfu_lo(u1);
        ay += bfu_hi(u0) + bfu_hi(u1);
    }
    for (; j < m; j += 2) {               // ragged tail (0..1 edges per sub)
        int jj = j + sub;
        int s = __shfl(eHeld, jj < m ? jj : 0, 64);
        if (jj < m) {
            unsigned u = *(const unsigned*)&h1s[((size_t)s << 6) + fp];
            ax += bfu_lo(u);
            ay += bfu_hi(u);
        }
    }
    for (int t = 64; t < dn; ++t) {       // deg > 64: astronomically rare here
        if (sub == 0) {
            int s = eidx[rs + t];
            unsigned u = *(const unsigned*)&h1s[((size_t)s << 6) + fp];
            ax += bfu_lo(u);
            ay += bfu_hi(u);
        }
    }
    // reduce across the 2 edge subgroups (both halves end with full sums)
    ax += __shfl_xor(ax, 32, 64);
    ay += __shfl_xor(ay, 32, 64);
    float di = dis[node];
    float2 bv = ((const float2*)b1)[lane & 31];
    float4 w = ((const float4*)W2)[lane & 31];   // W2[fp][0..1], W2[fp+1][0..1]
    float t0 = fmaxf(di * ax + bv.x, 0.f);
    float t1 = fmaxf(di * ay + bv.y, 0.f);
    float v0 = t0 * w.x + t1 * w.z;
    float v1 = t0 * w.y + t1 * w.w;
#pragma unroll
    for (int off = 1; off <= 16; off <<= 1) {   // sum the 32 feature classes
        v0 += __shfl_xor(v0, off, 64);
        v1 += __shfl_xor(v1, off, 64);
    }
    if (lane == 0) {
        h2s[(size_t)node * 2 + 0] = di * v0;
        h2s[(size_t)node * 2 + 1] = di * v1;
    }
}

// ---------- layer-2 gather: 16 lanes per node, one lane per edge ----------
__global__ void gather2_kernel(const int* __restrict__ rowstart,
                               const int* __restrict__ eidx, const float* __restrict__ dis,
                               const float2* __restrict__ h2s, const float* __restrict__ b2,
                               float2* __restrict__ out, int n) {
    int tid = threadIdx.x;
    int node = blockIdx.x * 16 + (tid >> 4);
    if (node >= n) return;
    int el = tid & 15;
    int rs = rowstart[node];
    int dn = rowstart[node + 1] - rs;
    float ax = 0.f, ay = 0.f;
    for (int t = el; t < dn; t += 16) {   // 16 edges in flight per node
        int s = eidx[rs + t];
        float2 h = h2s[s];
        ax += h.x;
        ay += h.y;
    }
#pragma unroll
    for (int off = 1; off <= 8; off <<= 1) {
        ax += __shfl_xor(ax, off, 64);
        ay += __shfl_xor(ay, off, 64);
    }
    if (el == 0) {
        float di = dis[node];
        out[node] = make_float2(di * ax + b2[0], di * ay + b2[1]);
    }
}

extern "C" void kernel_launch(void* const* d_in, const int* in_sizes, int n_in,
                              void* d_out, int out_size, void* d_ws, size_t ws_size,
                              hipStream_t stream) {
    const float* x  = (const float*)d_in[0];
    const int*   ei = (const int*)d_in[1];
    const float* W1 = (const float*)d_in[2];
    const float* b1 = (const float*)d_in[3];
    const float* W2 = (const float*)d_in[4];
    const float* b2 = (const float*)d_in[5];
    float2* out = (float2*)d_out;

    const int n = in_sizes[0] / 64;   // 100000
    const int e = in_sizes[1] / 2;    // 1600000
    const int* srcI = ei;
    const int* dstI = ei + e;
    const int nbkt = (n + NPB - 1) >> NPB_SHIFT;   // 391

    // workspace layout (256-B aligned segments); sums+cursor adjacent -> 1 memset
    char* p = (char*)d_ws;
    int* rowstart = (int*)p;    p += ((size_t)(n + 1) * 4 + 255) & ~255ull;
    float* dis    = (float*)p;  p += ((size_t)n * 4 + 255) & ~255ull;
    float* sums   = (float*)p;                  // 256 B
    int* cursor   = (int*)(p + 256);            // nbkt * 128-B padded slots
    size_t zsize  = 256 + (size_t)nbkt * CUR_STRIDE * 4;
    char* zbase   = p;          p += (zsize + 255) & ~255ull;
    float* cvec   = (float*)p;  p += 256;
    unsigned short* wtg = (unsigned short*)p;  p += (4096 * 2 + 255) & ~255ull;
    int* eidx     = (int*)p;    p += ((size_t)e * 4 + 255) & ~255ull;
    // union: pairs (8.0 MB packed) dead before gemm1 writes h1s (bf16, 12.8 MB)
    unsigned* pairs      = (unsigned*)p;
    unsigned short* h1s  = (unsigned short*)p;
    {
        size_t pairs_sz = (size_t)nbkt * BKT_CAP * 4;
        size_t h1s_sz   = (size_t)n * 64 * 2;
        size_t u = pairs_sz > h1s_sz ? pairs_sz : h1s_sz;
        p += (u + 255) & ~255ull;
    }
    float* h2s    = (float*)p;

    hipMemsetAsync(zbase, 0, zsize, stream);

    const int nchunks = (e + CHUNK - 1) / CHUNK;           // 391

    bucketAC_kernel<<<CS_BLK + 1 + nchunks, 512, 0, stream>>>(srcI, dstI, e, pairs, cursor,
                                                              x, sums, W1, wtg, n);
    csrB_kernel<<<nbkt, 512, 0, stream>>>(pairs, cursor, dis, rowstart, eidx, n,
                                          sums, W1, cvec);
    gemm1_kernel<<<(n + 63) / 64, 256, 0, stream>>>(x, wtg, cvec, dis, h1s, n);
    gather1_kernel<<<(n + 3) / 4, 256, 0, stream>>>(rowstart, eidx, dis, h1s, b1, W2, h2s, n);
    gather2_kernel<<<(n + 15) / 16, 256, 0, stream>>>(rowstart, eidx, dis, (const float2*)h2s,
                                                      b2, out, n);
}

// Round 13
// 185.694 us; speedup vs baseline: 4.6927x; 1.0053x over previous
//
#include <hip/hip_runtime.h>

// GCN 2-layer, CSR-by-dst gather formulation; h1s in bf16.
// R12: gemm1 fused into csrB (csrBG): each bucket block CSR-fills its 256
//      nodes then runs their 4x64-row MFMA tiles (2 tiles on 8 waves, 2 iters).
//      5 dispatches: memset, bucketAC, csrBG, gather1, gather2.
// gather1 frozen at its measured floor (~44us, L2-miss-path bound: R10 4-deep
// and R11 8-deep MLP both 43-45us at FETCH 81 MB).
// out = A_hat( relu( A_hat( [x|mean]@W1 ) + b1 ) @ W2 ) + b2
// Identity: [x|mean]@W1 = x@W1[:64] + c, c = mean@W1[64:].
// Pre-scaling: h1s[s] = dis[s]*(xW1+c)[s];  h2s[s] = dis[s]*(relu(.)@W2)[s].

#define NPB        256     // nodes per bucket
#define NPB_SHIFT  8
#define BKTS       512     // scan width (>= 391 buckets, pow2)
#define BKT_CAP    5120    // mean 4096 + 16 sigma
#define CHUNK      4096    // edges per bucketA block
#define EPT        8       // CHUNK / 512 threads
#define CS_BLK     64      // colsum blocks prepended to bucketA grid
#define CUR_STRIDE 32      // ints per cursor slot (128-B line each)

using bf16x8 = __attribute__((ext_vector_type(8))) short;  // 8 bf16 (4 VGPRs)
using f32x4  = __attribute__((ext_vector_type(4))) float;

__device__ __forceinline__ unsigned short f2bf(float v) {
    unsigned u = __float_as_uint(v);
    u += 0x7FFFu + ((u >> 16) & 1u);   // round-to-nearest-even
    return (unsigned short)(u >> 16);
}
// two bf16 packed in a uint -> two floats (2 VALU)
__device__ __forceinline__ float bfu_lo(unsigned u) { return __uint_as_float(u << 16); }
__device__ __forceinline__ float bfu_hi(unsigned u) { return __uint_as_float(u & 0xFFFF0000u); }

// ---------- pass A: colsum (0..63) + W^T->bf16 (64) + multi-split (rest) ----------
__global__ __launch_bounds__(512) void bucketAC_kernel(
        const int* __restrict__ src, const int* __restrict__ dst,
        int e, unsigned* __restrict__ pairs, int* __restrict__ cursor,
        const float* __restrict__ x, float* __restrict__ sums,
        const float* __restrict__ W1, unsigned short* __restrict__ wtg, int n) {
    int tid = threadIdx.x;
    if (blockIdx.x < CS_BLK) {
        // ---- colsum side-job: column sums of x via float4 grid-stride ----
        __shared__ float4 s4[512];
        int cb = blockIdx.x;
        const float4* x4 = (const float4*)x;
        int total4 = n * 16;
        float4 acc = make_float4(0.f, 0.f, 0.f, 0.f);
        for (int i = cb * 512 + tid; i < total4; i += CS_BLK * 512) {
            float4 v = x4[i];
            acc.x += v.x; acc.y += v.y; acc.z += v.z; acc.w += v.w;
        }
        s4[tid] = acc;
        __syncthreads();
        if (tid < 16) {
            float4 v = s4[tid];
            for (int k = 1; k < 32; ++k) {
                float4 w = s4[tid + 16 * k];
                v.x += w.x; v.y += w.y; v.z += w.z; v.w += w.w;
            }
            atomicAdd(&sums[tid * 4 + 0], v.x);
            atomicAdd(&sums[tid * 4 + 1], v.y);
            atomicAdd(&sums[tid * 4 + 2], v.z);
            atomicAdd(&sums[tid * 4 + 3], v.w);
        }
        return;
    }
    if (blockIdx.x == CS_BLK) {
        // ---- W transpose side-job: wtg[j*64+k] = bf16(W1[k*64+j]), k<64 ----
        for (int i = tid; i < 4096; i += 512) {
            int k = i >> 6, j = i & 63;
            wtg[j * 64 + k] = f2bf(W1[k * 64 + j]);
        }
        return;
    }
    // ---- bucket multi-split: packed 4-B records (src<<8 | dst&255) ----
    __shared__ int cnt[BKTS], sb[BKTS], gpos[BKTS];
    __shared__ unsigned stage[CHUNK];
    __shared__ unsigned short bb[CHUNK];
    int chunkStart = (blockIdx.x - CS_BLK - 1) * CHUNK;
    int v = e - chunkStart;
    if (v > CHUNK) v = CHUNK;
    cnt[tid] = 0;
    __syncthreads();
    int myb[EPT], myoff[EPT];
    unsigned myp[EPT];
#pragma unroll
    for (int t = 0; t < EPT; ++t) {
        int i = chunkStart + t * 512 + tid;
        myb[t] = -1;
        if (i < e) {
            int s = src[i], d = dst[i];
            myb[t] = d >> NPB_SHIFT;
            myp[t] = ((unsigned)s << NPB_SHIFT) | (unsigned)(d & (NPB - 1));
            myoff[t] = atomicAdd(&cnt[myb[t]], 1);
        }
    }
    __syncthreads();
    sb[tid] = cnt[tid];
    __syncthreads();
    for (int off = 1; off < BKTS; off <<= 1) {
        int t = (tid >= off) ? sb[tid - off] : 0;
        __syncthreads();
        sb[tid] += t;
        __syncthreads();
    }
    {
        int excl = tid ? sb[tid - 1] : 0;
        int cb = cnt[tid];
        if (cb > 0) {
            int gb = atomicAdd(&cursor[tid * CUR_STRIDE], cb);  // private line
            gpos[tid] = tid * BKT_CAP + gb - excl;
        }
        cnt[tid] = excl;  // reuse as stage base
    }
    __syncthreads();
#pragma unroll
    for (int t = 0; t < EPT; ++t) {
        if (myb[t] >= 0) {
            int p = cnt[myb[t]] + myoff[t];
            stage[p] = myp[t];
            bb[p] = (unsigned short)myb[t];
        }
    }
    __syncthreads();
    for (int j = tid; j < v; j += 512) {
        int bk = bb[j];
        int wi = gpos[bk] + j;
        if (wi < (bk + 1) * BKT_CAP) pairs[wi] = stage[j];  // contiguous runs
    }
}

// ---------- pass B fused: CSR (hist+scan+fill) + cvec + MFMA gemm for own rows ----------
__global__ __launch_bounds__(512) void csrBG_kernel(
        const unsigned* __restrict__ pairs, const int* __restrict__ cursor,
        float* __restrict__ dis, int* __restrict__ rowstart,
        int* __restrict__ eidx, int n,
        const float* __restrict__ sums, const float* __restrict__ W1,
        const unsigned short* __restrict__ wtg, const float* __restrict__ x,
        unsigned short* __restrict__ h1s) {
    __shared__ int ldeg[NPB];       // later reused as float dis bits
    __shared__ int lcur[NPB];
    __shared__ int scanbuf[512];
    __shared__ int s_ebase;
    __shared__ __align__(16) float cv[64];
    __shared__ unsigned short Ws[64 * 72];       // W^T bf16, stride 72
    __shared__ unsigned short Xs[2][64 * 72];    // 2 tiles
    float* disl = (float*)ldeg;
    int b = blockIdx.x;
    int tid = threadIdx.x;
    int node0 = b << NPB_SHIFT;
    int nl = n - node0;
    if (nl > NPB) nl = NPB;
    int cnt_b = cursor[b * CUR_STRIDE];
    if (cnt_b > BKT_CAP) cnt_b = BKT_CAP;
    if (tid < NPB) ldeg[tid] = 0;
    if (tid == 0) s_ebase = 0;
    __syncthreads();
    if (tid < b) atomicAdd(&s_ebase, cursor[tid * CUR_STRIDE]);  // parallel prefix
    const unsigned* mp = pairs + (size_t)b * BKT_CAP;
    for (int i = tid; i < cnt_b; i += 512)
        atomicAdd(&ldeg[mp[i] & (NPB - 1)], 1);
    __syncthreads();
    scanbuf[tid] = (tid < NPB) ? ldeg[tid] : 0;
    __syncthreads();
    for (int off = 1; off < 512; off <<= 1) {
        int t = (tid >= off) ? scanbuf[tid - off] : 0;
        __syncthreads();
        scanbuf[tid] += t;
        __syncthreads();
    }
    int ebase = s_ebase;
    int mydeg = 0;
    if (tid < NPB) {
        int ex = tid ? scanbuf[tid - 1] : 0;
        lcur[tid] = ex;
        mydeg = ldeg[tid];
        if (tid < nl) rowstart[node0 + tid] = ebase + ex;
    }
    if (tid == 0 && node0 + NPB >= n)          // last bucket: close the CSR
        rowstart[n] = ebase + cnt_b;
    __syncthreads();
    // overwrite ldeg with dis (float bits); scan/hist done, lcur carries cursors
    if (tid < NPB) {
        float dv = mydeg > 0 ? rsqrtf((float)mydeg) : 0.f;
        disl[tid] = dv;
        if (tid < nl) dis[node0 + tid] = dv;
    }
    for (int i = tid; i < cnt_b; i += 512) {
        unsigned p = mp[i];
        int pos = atomicAdd(&lcur[p & (NPB - 1)], 1);
        eidx[ebase + pos] = (int)(p >> NPB_SHIFT);  // contiguous ~16 KB window
    }
    // ---- cvec (redundant per block, trivial) ----
    if (tid < 64) {
        float inv_n = 1.0f / (float)n;
        float acc = 0.f;
        for (int k = 0; k < 64; ++k) acc += (sums[k] * inv_n) * W1[(64 + k) * 64 + tid];
        cv[tid] = acc;
    }
    // ---- stage W^T once ----
    for (int i = tid; i < 1024; i += 512) {
        int j = i >> 4, k4 = (i & 15) * 4;
        *(ushort4*)&Ws[j * 72 + k4] = *(const ushort4*)&wtg[j * 64 + k4];
    }
    // ---- gemm: 256 rows = 2 iters x 2 tiles x 64 rows ----
    int lane = tid & 63;
    int wv = tid >> 6;          // 0..7
    int tile = wv >> 2;         // 0..1
    int w4 = wv & 3;            // wave within tile
    int l15 = lane & 15;
    int quad = lane >> 4;
#pragma unroll
    for (int it = 0; it < 2; ++it) {
        __syncthreads();
        // stage 128 rows (2 tiles) of x -> bf16
        for (int i = tid; i < 2048; i += 512) {
            int r = i >> 4, k4 = (i & 15) * 4;
            int gr = node0 + it * 128 + r;
            float4 xv = make_float4(0.f, 0.f, 0.f, 0.f);
            if (gr < n) xv = *(const float4*)&x[(size_t)gr * 64 + k4];
            ushort4 hv;
            hv.x = f2bf(xv.x); hv.y = f2bf(xv.y); hv.z = f2bf(xv.z); hv.w = f2bf(xv.w);
            *(ushort4*)&Xs[r >> 6][(r & 63) * 72 + k4] = hv;
        }
        __syncthreads();
        int xrow = w4 * 16 + l15;                    // row within tile
        f32x4 acc0 = {0.f, 0.f, 0.f, 0.f}, acc1 = acc0, acc2 = acc0, acc3 = acc0;
#pragma unroll
        for (int ks = 0; ks < 2; ++ks) {
            bf16x8 bfrag = *(const bf16x8*)&Xs[tile][xrow * 72 + ks * 32 + quad * 8];
            bf16x8 a0 = *(const bf16x8*)&Ws[(0 * 16 + l15) * 72 + ks * 32 + quad * 8];
            bf16x8 a1 = *(const bf16x8*)&Ws[(1 * 16 + l15) * 72 + ks * 32 + quad * 8];
            bf16x8 a2 = *(const bf16x8*)&Ws[(2 * 16 + l15) * 72 + ks * 32 + quad * 8];
            bf16x8 a3 = *(const bf16x8*)&Ws[(3 * 16 + l15) * 72 + ks * 32 + quad * 8];
            acc0 = __builtin_amdgcn_mfma_f32_16x16x32_bf16(a0, bfrag, acc0, 0, 0, 0);
            acc1 = __builtin_amdgcn_mfma_f32_16x16x32_bf16(a1, bfrag, acc1, 0, 0, 0);
            acc2 = __builtin_amdgcn_mfma_f32_16x16x32_bf16(a2, bfrag, acc2, 0, 0, 0);
            acc3 = __builtin_amdgcn_mfma_f32_16x16x32_bf16(a3, bfrag, acc3, 0, 0, 0);
        }
        int lrow = it * 128 + tile * 64 + xrow;      // row within bucket
        int grow = node0 + lrow;
        if (grow < n) {
            float dv = disl[lrow];
            const float4* c4 = (const float4*)cv;
            f32x4 accs[4] = {acc0, acc1, acc2, acc3};
#pragma unroll
            for (int t = 0; t < 4; ++t) {
                float4 cj = c4[t * 4 + quad];
                ushort4 hs;
                hs.x = f2bf((accs[t][0] + cj.x) * dv);
                hs.y = f2bf((accs[t][1] + cj.y) * dv);
                hs.z = f2bf((accs[t][2] + cj.z) * dv);
                hs.w = f2bf((accs[t][3] + cj.w) * dv);
                *(ushort4*)&h1s[(size_t)grow * 64 + t * 16 + quad * 4] = hs;
            }
        }
    }
}

// ---------- layer-1 gather: 32 lanes/edge (ushort2/lane), 8 loads in flight ----------
__global__ void gather1_kernel(const int* __restrict__ rowstart,
                               const int* __restrict__ eidx, const float* __restrict__ dis,
                               const unsigned short* __restrict__ h1s,
                               const float* __restrict__ b1, const float* __restrict__ W2,
                               float* __restrict__ h2s, int n) {
    int lane = threadIdx.x & 63;
    int node = blockIdx.x * 4 + (threadIdx.x >> 6);
    if (node >= n) return;
    int rs = rowstart[node];
    int re = rowstart[node + 1];
    int dn = re - rs;
    int m = dn < 64 ? dn : 64;
    int eHeld = (lane < m) ? eidx[rs + lane] : 0;  // one coalesced load for <=64 edges
    int sub = lane >> 5;        // edge subgroup 0..1
    int fp  = (lane & 31) * 2;  // feature pair base
    float ax = 0.f, ay = 0.f;
    int j = 0;
    for (; j + 16 <= m; j += 16) {        // 16 edges per iter, 8 loads in flight
        int s0 = __shfl(eHeld, j + 0 + sub, 64);
        int s1 = __shfl(eHeld, j + 2 + sub, 64);
        int s2 = __shfl(eHeld, j + 4 + sub, 64);
        int s3 = __shfl(eHeld, j + 6 + sub, 64);
        int s4 = __shfl(eHeld, j + 8 + sub, 64);
        int s5 = __shfl(eHeld, j + 10 + sub, 64);
        int s6 = __shfl(eHeld, j + 12 + sub, 64);
        int s7 = __shfl(eHeld, j + 14 + sub, 64);
        unsigned u0 = *(const unsigned*)&h1s[((size_t)s0 << 6) + fp];
        unsigned u1 = *(const unsigned*)&h1s[((size_t)s1 << 6) + fp];
        unsigned u2 = *(const unsigned*)&h1s[((size_t)s2 << 6) + fp];
        unsigned u3 = *(const unsigned*)&h1s[((size_t)s3 << 6) + fp];
        unsigned u4 = *(const unsigned*)&h1s[((size_t)s4 << 6) + fp];
        unsigned u5 = *(const unsigned*)&h1s[((size_t)s5 << 6) + fp];
        unsigned u6 = *(const unsigned*)&h1s[((size_t)s6 << 6) + fp];
        unsigned u7 = *(const unsigned*)&h1s[((size_t)s7 << 6) + fp];
        ax += (bfu_lo(u0) + bfu_lo(u1)) + (bfu_lo(u2) + bfu_lo(u3))
            + (bfu_lo(u4) + bfu_lo(u5)) + (bfu_lo(u6) + bfu_lo(u7));
        ay += (bfu_hi(u0) + bfu_hi(u1)) + (bfu_hi(u2) + bfu_hi(u3))
            + (bfu_hi(u4) + bfu_hi(u5)) + (bfu_hi(u6) + bfu_hi(u7));
    }
    for (; j + 8 <= m; j += 8) {          // 8-edge tail, 4 loads
        int s0 = __shfl(eHeld, j + 0 + sub, 64);
        int s1 = __shfl(eHeld, j + 2 + sub, 64);
        int s2 = __shfl(eHeld, j + 4 + sub, 64);
        int s3 = __shfl(eHeld, j + 6 + sub, 64);
        unsigned u0 = *(const unsigned*)&h1s[((size_t)s0 << 6) + fp];
        unsigned u1 = *(const unsigned*)&h1s[((size_t)s1 << 6) + fp];
        unsigned u2 = *(const unsigned*)&h1s[((size_t)s2 << 6) + fp];
        unsigned u3 = *(const unsigned*)&h1s[((size_t)s3 << 6) + fp];
        ax += (bfu_lo(u0) + bfu_lo(u1)) + (bfu_lo(u2) + bfu_lo(u3));
        ay += (bfu_hi(u0) + bfu_hi(u1)) + (bfu_hi(u2) + bfu_hi(u3));
    }
    for (; j + 4 <= m; j += 4) {          // 4-edge tail, 2 loads
        int s0 = __shfl(eHeld, j + 0 + sub, 64);
        int s1 = __shfl(eHeld, j + 2 + sub, 64);
        unsigned u0 = *(const unsigned*)&h1s[((size_t)s0 << 6) + fp];
        unsigned u1 = *(const unsigned*)&h1s[((size_t)s1 << 6) + fp];
        ax += bfu_lo(u0) + bfu_lo(u1);
        ay += bfu_hi(u0) + bfu_hi(u1);
    }
    for (; j < m; j += 2) {               // ragged tail (0..1 edges per sub)
        int jj = j + sub;
        int s = __shfl(eHeld, jj < m ? jj : 0, 64);
        if (jj < m) {
            unsigned u = *(const unsigned*)&h1s[((size_t)s << 6) + fp];
            ax += bfu_lo(u);
            ay += bfu_hi(u);
        }
    }
    for (int t = 64; t < dn; ++t) {       // deg > 64: astronomically rare here
        if (sub == 0) {
            int s = eidx[rs + t];
            unsigned u = *(const unsigned*)&h1s[((size_t)s << 6) + fp];
            ax += bfu_lo(u);
            ay += bfu_hi(u);
        }
    }
    // reduce across the 2 edge subgroups (both halves end with full sums)
    ax += __shfl_xor(ax, 32, 64);
    ay += __shfl_xor(ay, 32, 64);
    float di = dis[node];
    float2 bv = ((const float2*)b1)[lane & 31];
    float4 w = ((const float4*)W2)[lane & 31];   // W2[fp][0..1], W2[fp+1][0..1]
    float t0 = fmaxf(di * ax + bv.x, 0.f);
    float t1 = fmaxf(di * ay + bv.y, 0.f);
    float v0 = t0 * w.x + t1 * w.z;
    float v1 = t0 * w.y + t1 * w.w;
#pragma unroll
    for (int off = 1; off <= 16; off <<= 1) {   // sum the 32 feature classes
        v0 += __shfl_xor(v0, off, 64);
        v1 += __shfl_xor(v1, off, 64);
    }
    if (lane == 0) {
        h2s[(size_t)node * 2 + 0] = di * v0;
        h2s[(size_t)node * 2 + 1] = di * v1;
    }
}

// ---------- layer-2 gather: 16 lanes per node, one lane per edge ----------
__global__ void gather2_kernel(const int* __restrict__ rowstart,
                               const int* __restrict__ eidx, const float* __restrict__ dis,
                               const float2* __restrict__ h2s, const float* __restrict__ b2,
                               float2* __restrict__ out, int n) {
    int tid = threadIdx.x;
    int node = blockIdx.x * 16 + (tid >> 4);
    if (node >= n) return;
    int el = tid & 15;
    int rs = rowstart[node];
    int dn = rowstart[node + 1] - rs;
    float ax = 0.f, ay = 0.f;
    for (int t = el; t < dn; t += 16) {   // 16 edges in flight per node
        int s = eidx[rs + t];
        float2 h = h2s[s];
        ax += h.x;
        ay += h.y;
    }
#pragma unroll
    for (int off = 1; off <= 8; off <<= 1) {
        ax += __shfl_xor(ax, off, 64);
        ay += __shfl_xor(ay, off, 64);
    }
    if (el == 0) {
        float di = dis[node];
        out[node] = make_float2(di * ax + b2[0], di * ay + b2[1]);
    }
}

extern "C" void kernel_launch(void* const* d_in, const int* in_sizes, int n_in,
                              void* d_out, int out_size, void* d_ws, size_t ws_size,
                              hipStream_t stream) {
    const float* x  = (const float*)d_in[0];
    const int*   ei = (const int*)d_in[1];
    const float* W1 = (const float*)d_in[2];
    const float* b1 = (const float*)d_in[3];
    const float* W2 = (const float*)d_in[4];
    const float* b2 = (const float*)d_in[5];
    float2* out = (float2*)d_out;

    const int n = in_sizes[0] / 64;   // 100000
    const int e = in_sizes[1] / 2;    // 1600000
    const int* srcI = ei;
    const int* dstI = ei + e;
    const int nbkt = (n + NPB - 1) >> NPB_SHIFT;   // 391

    // workspace layout (256-B aligned segments); sums+cursor adjacent -> 1 memset
    char* p = (char*)d_ws;
    int* rowstart = (int*)p;    p += ((size_t)(n + 1) * 4 + 255) & ~255ull;
    float* dis    = (float*)p;  p += ((size_t)n * 4 + 255) & ~255ull;
    float* sums   = (float*)p;                  // 256 B
    int* cursor   = (int*)(p + 256);            // nbkt * 128-B padded slots
    size_t zsize  = 256 + (size_t)nbkt * CUR_STRIDE * 4;
    char* zbase   = p;          p += (zsize + 255) & ~255ull;
    unsigned short* wtg = (unsigned short*)p;  p += (4096 * 2 + 255) & ~255ull;
    int* eidx     = (int*)p;    p += ((size_t)e * 4 + 255) & ~255ull;
    // union: pairs (8.0 MB packed) dead before csrBG writes h1s (bf16, 12.8 MB)
    // NOTE: csrBG writes h1s rows [node0, node0+256) AFTER consuming its own
    // pairs bucket [b*CAP, (b+1)*CAP)... bucket b's pairs live at byte offset
    // b*20480, its h1s rows at byte offset b*32768 -> h1s writes of bucket b
    // land PAST its pairs region only for later buckets' pairs. To be safe,
    // keep pairs and h1s in SEPARATE regions (no union) - ws is large enough.
    unsigned* pairs = (unsigned*)p;  p += ((size_t)nbkt * BKT_CAP * 4 + 255) & ~255ull;
    unsigned short* h1s = (unsigned short*)p;  p += ((size_t)n * 64 * 2 + 255) & ~255ull;
    float* h2s    = (float*)p;

    hipMemsetAsync(zbase, 0, zsize, stream);

    const int nchunks = (e + CHUNK - 1) / CHUNK;           // 391

    bucketAC_kernel<<<CS_BLK + 1 + nchunks, 512, 0, stream>>>(srcI, dstI, e, pairs, cursor,
                                                              x, sums, W1, wtg, n);
    csrBG_kernel<<<nbkt, 512, 0, stream>>>(pairs, cursor, dis, rowstart, eidx, n,
                                           sums, W1, wtg, x, h1s);
    gather1_kernel<<<(n + 3) / 4, 256, 0, stream>>>(rowstart, eidx, dis, h1s, b1, W2, h2s, n);
    gather2_kernel<<<(n + 15) / 16, 256, 0, stream>>>(rowstart, eidx, dis, (const float2*)h2s,
                                                      b2, out, n);
}